// Round 3
// baseline (868.818 us; speedup 1.0000x reference)
//
#include <hip/hip_runtime.h>
#include <stdint.h>

#define T_TOKENS 8192
#define D_DIM 1024
#define H_DIM 2048
#define E_NUM 8
#define MAXP 18432         // pairs padded to 256/expert: 16384 + 8*255 <= 18432
#define MAXT 72            // max sum of per-expert ceil(cnt/256)

typedef __attribute__((ext_vector_type(8))) short short8;
typedef __attribute__((ext_vector_type(4))) float f32x4;
typedef __attribute__((ext_vector_type(8))) unsigned short u16x8;

__device__ __forceinline__ unsigned short f2bf(float f) {
  union { float f; uint32_t u; } v; v.f = f;
  uint32_t r = (v.u + 0x7fffu + ((v.u >> 16) & 1u)) >> 16;
  return (unsigned short)r;
}

__device__ __forceinline__ void gload16(const void* g, void* l) {
  __builtin_amdgcn_global_load_lds((const __attribute__((address_space(1))) void*)g,
                                   (__attribute__((address_space(3))) void*)l, 16, 0, 0);
}

// ---------------- router: logits (f64 accum), top-2, softmax, counts ----------------
__global__ void router_kernel(const float* __restrict__ x, const float* __restrict__ Wg,
                              int* __restrict__ cnt, int* __restrict__ tok_e01,
                              float* __restrict__ tok_w) {
  __shared__ float wgT[E_NUM * D_DIM];
  int tid = threadIdx.x;
  for (int i = tid; i < D_DIM * E_NUM; i += 256) {
    int d = i >> 3, e = i & 7;
    wgT[e * D_DIM + d] = Wg[i];
  }
  __syncthreads();
  int wid = tid >> 6, lane = tid & 63;
  int t = blockIdx.x * 4 + wid;
  const float* xr = x + (size_t)t * D_DIM;
  double acc[E_NUM];
#pragma unroll
  for (int e = 0; e < E_NUM; e++) acc[e] = 0.0;
  for (int i = 0; i < D_DIM / 64; i++) {
    double xv = (double)xr[i * 64 + lane];
#pragma unroll
    for (int e = 0; e < E_NUM; e++) acc[e] += xv * (double)wgT[e * D_DIM + i * 64 + lane];
  }
#pragma unroll
  for (int e = 0; e < E_NUM; e++) {
    double v = acc[e];
#pragma unroll
    for (int off = 32; off >= 1; off >>= 1) v += __shfl_xor(v, off);
    acc[e] = v;
  }
  if (lane == 0) {
    int e0 = 0; double l0 = acc[0];
#pragma unroll
    for (int e = 1; e < E_NUM; e++) if (acc[e] > l0) { l0 = acc[e]; e0 = e; }
    int e1 = -1; double l1 = -1e300;
#pragma unroll
    for (int e = 0; e < E_NUM; e++) if (e != e0 && acc[e] > l1) { l1 = acc[e]; e1 = e; }
    float z1 = expf((float)(l1 - l0));
    float w0 = 1.f / (1.f + z1);
    float w1 = z1 * w0;
    tok_e01[t] = e0 | (e1 << 8);
    tok_w[2 * t] = w0; tok_w[2 * t + 1] = w1;
    atomicAdd(&cnt[e0], 1);
    atomicAdd(&cnt[e1], 1);
  }
}

// 256-aligned per-expert segments + static tile table
__global__ void scan_kernel(const int* __restrict__ cnt, int* __restrict__ poffs,
                            int* __restrict__ tile2e, int* __restrict__ tile_row0) {
  if (threadIdx.x == 0) {
    int po = 0, tf = 0;
    for (int e = 0; e < E_NUM; e++) {
      poffs[e] = po;
      int nt = (cnt[e] + 255) >> 8;
      for (int i = 0; i < nt; i++) { tile2e[tf] = e; tile_row0[tf] = po + i * 256; tf++; }
      po += nt << 8;
    }
    for (; tf < MAXT; tf++) { tile2e[tf] = -1; tile_row0[tf] = 0; }
  }
}

__global__ void assign_kernel(const int* __restrict__ tok_e01, const float* __restrict__ tok_w,
                              const int* __restrict__ poffs, int* __restrict__ run,
                              int* __restrict__ pair_tok, float* __restrict__ pair_w) {
  int t = blockIdx.x * 256 + threadIdx.x;
  if (t >= T_TOKENS) return;
  int p = tok_e01[t];
  int e0 = p & 255, e1 = (p >> 8) & 255;
  int pos0 = poffs[e0] + atomicAdd(&run[e0], 1);
  pair_tok[pos0] = t; pair_w[pos0] = tok_w[2 * t];
  int pos1 = poffs[e1] + atomicAdd(&run[e1], 1);
  pair_tok[pos1] = t; pair_w[pos1] = tok_w[2 * t + 1];
}

// ---------------- casts ----------------
__global__ void cast_x_kernel(const float* __restrict__ x, unsigned short* __restrict__ xb) {
  int i = blockIdx.x * 256 + threadIdx.x;
  const float4* xp = (const float4*)x;
  float4 a = xp[2 * i], b = xp[2 * i + 1];
  u16x8 r;
  r[0] = f2bf(a.x); r[1] = f2bf(a.y); r[2] = f2bf(a.z); r[3] = f2bf(a.w);
  r[4] = f2bf(b.x); r[5] = f2bf(b.y); r[6] = f2bf(b.z); r[7] = f2bf(b.w);
  *(u16x8*)(xb + (size_t)i * 8) = r;
}

// W3: [E][H][D] f32 -> [E][D][H] bf16 (N-major, K contiguous)
__global__ void cast_transpose_kernel(const float* __restrict__ in, unsigned short* __restrict__ out,
                                      int R, int C) {
  __shared__ float tile[32][33];
  int e = blockIdx.z;
  const float* src = in + (size_t)e * R * C;
  unsigned short* dst = out + (size_t)e * R * C;
  int c0 = blockIdx.x * 32, r0 = blockIdx.y * 32;
  int tx = threadIdx.x, ty = threadIdx.y;
#pragma unroll
  for (int i = 0; i < 4; i++)
    tile[ty + i * 8][tx] = src[(size_t)(r0 + ty + i * 8) * C + c0 + tx];
  __syncthreads();
#pragma unroll
  for (int i = 0; i < 4; i++)
    dst[(size_t)(c0 + ty + i * 8) * R + r0 + tx] = f2bf(tile[tx][ty + i * 8]);
}

// W1/W2: [E][D][H] f32 -> Bcat [E][4096][1024] bf16, 16-col interleave (u then v per 32-row group)
__global__ void cast_transpose_cat_kernel(const float* __restrict__ in, unsigned short* __restrict__ Bcat,
                                          int isV) {
  __shared__ float tile[32][33];
  int e = blockIdx.z;
  const float* src = in + (size_t)e * D_DIM * H_DIM;
  unsigned short* dst = Bcat + (size_t)e * 4096 * 1024;
  int c0 = blockIdx.x * 32, r0 = blockIdx.y * 32;
  int tx = threadIdx.x, ty = threadIdx.y;
#pragma unroll
  for (int i = 0; i < 4; i++)
    tile[ty + i * 8][tx] = src[(size_t)(r0 + ty + i * 8) * H_DIM + c0 + tx];
  __syncthreads();
#pragma unroll
  for (int i = 0; i < 4; i++) {
    int n = c0 + ty + i * 8;
    int nr = ((n >> 4) << 5) + (n & 15) + isV * 16;
    dst[(size_t)nr * 1024 + r0 + tx] = f2bf(tile[tx][ty + i * 8]);
  }
}

// ---------------- deep-pipelined GEMM phase ----------------
// per phase: 12x ds_read_b128 ; stage 1 k-half (4x global_load_lds) ; vmcnt(VM) ;
// barrier ; setprio1 ; 32 MFMA ; setprio0 ; barrier
template <int VM, typename F>
__device__ __forceinline__ void phase_fn(f32x4 (&acc)[4][8], const char* Ak, const char* Bk,
                                         int aB, int bB, F stg) {
  short8 af[4], bf[8];
#pragma unroll
  for (int mf = 0; mf < 4; mf++) af[mf] = *(const short8*)(Ak + aB + mf * 1024);
#pragma unroll
  for (int nf = 0; nf < 8; nf++) bf[nf] = *(const short8*)(Bk + bB + nf * 1024);
  stg();
  if (VM == 8)      asm volatile("s_waitcnt vmcnt(8)" ::: "memory");
  else if (VM == 4) asm volatile("s_waitcnt vmcnt(4)" ::: "memory");
  else              asm volatile("s_waitcnt vmcnt(0)" ::: "memory");
  __builtin_amdgcn_s_barrier();
  __builtin_amdgcn_s_setprio(1);
#pragma unroll
  for (int mf = 0; mf < 4; mf++)
#pragma unroll
    for (int nf = 0; nf < 8; nf++)
      acc[mf][nf] = __builtin_amdgcn_mfma_f32_16x16x32_bf16(af[mf], bf[nf], acc[mf][nf], 0, 0, 0);
  __builtin_amdgcn_s_setprio(0);
  __builtin_amdgcn_sched_barrier(0);
  __builtin_amdgcn_s_barrier();
  __builtin_amdgcn_sched_barrier(0);
}

// ---------------- pass A: h = swish(x*W1) * (x*W2), fused via interleaved Bcat ----------------
// BM=BN=256, K=1024, BK=64 as 2 contiguous 32-k halves. 8 waves (4M x 2N), 128KB dyn LDS.
__global__ __launch_bounds__(512, 2) void ffn1_kernel(
    const unsigned short* __restrict__ xb, const unsigned short* __restrict__ Bcat,
    unsigned short* __restrict__ h_buf,
    const int* __restrict__ pair_tok, const int* __restrict__ tile2e,
    const int* __restrict__ tile_row0) {
  extern __shared__ char lds[];
  char* ldsA = lds;            // 4 regions of 16KB: (buf*2+kh)
  char* ldsB = lds + 65536;
  const int NWG = MAXT * 16;   // 1152, %8==0
  int orig = blockIdx.x;
  int wg = (orig & 7) * (NWG >> 3) + (orig >> 3);
  int f = wg >> 4, nt = wg & 15;
  int e = tile2e[f];
  if (e < 0) return;
  int row0 = tile_row0[f];

  int tid = threadIdx.x;
  int w = tid >> 6, lane = tid & 63;
  int l15 = lane & 15, g4 = lane >> 4;
  int wr = w >> 1, wc = w & 1;

  // staging: thread covers chunk rows rA and rA+128, source col pre-swizzled q^((r>>1)&3)
  int qs = (tid & 3) ^ ((tid >> 3) & 3);
  int rA = tid >> 2;                       // 0..127
  int tok0 = pair_tok[row0 + rA];
  int tok1 = pair_tok[row0 + rA + 128];
  const char* gA0 = (const char*)xb + (size_t)tok0 * 2048 + qs * 16;
  const char* gA1 = (const char*)xb + (size_t)tok1 * 2048 + qs * 16;
  const char* Bce = (const char*)Bcat + (size_t)e * 4096 * 2048;
  const char* gB0 = Bce + (size_t)(nt * 256 + rA) * 2048 + qs * 16;
  const char* gB1 = Bce + (size_t)(nt * 256 + rA + 128) * 2048 + qs * 16;

  auto STG = [&](int kt, int kh, int buf) {
    int off = kt * 128 + kh * 64;
    char* dA = ldsA + (buf * 2 + kh) * 16384 + w * 1024;
    char* dB = ldsB + (buf * 2 + kh) * 16384 + w * 1024;
    gload16(gA0 + off, dA);  gload16(gA1 + off, dA + 8192);
    gload16(gB0 + off, dB);  gload16(gB1 + off, dB + 8192);
  };

  // fragment reads: row = base + l15, chunk q = (lane>>4) ^ ((lane>>1)&3)  (matches stage swizzle)
  int qr = g4 ^ ((lane >> 1) & 3);
  int aB = wr * 4096 + l15 * 64 + qr * 16;
  int bB = wc * 8192 + l15 * 64 + qr * 16;

  f32x4 acc[4][8];
#pragma unroll
  for (int i = 0; i < 4; i++)
#pragma unroll
    for (int j = 0; j < 8; j++) acc[i][j] = (f32x4){0.f, 0.f, 0.f, 0.f};

  // prologue: K-tile0 both halves -> buf0, K-tile1 half0 -> buf1
  STG(0, 0, 0); STG(0, 1, 0); STG(1, 0, 1);
  asm volatile("s_waitcnt vmcnt(8)" ::: "memory");
  __builtin_amdgcn_s_barrier();

  const int NT = 16;  // K/64
#pragma unroll 1
  for (int t2 = 0; t2 < NT - 2; t2 += 2) {
    phase_fn<8>(acc, ldsA + 0 * 16384, ldsB + 0 * 16384, aB, bB, [&] { STG(t2 + 1, 1, 1); });
    phase_fn<8>(acc, ldsA + 1 * 16384, ldsB + 1 * 16384, aB, bB, [&] { STG(t2 + 2, 0, 0); });
    phase_fn<8>(acc, ldsA + 2 * 16384, ldsB + 2 * 16384, aB, bB, [&] { STG(t2 + 2, 1, 0); });
    phase_fn<8>(acc, ldsA + 3 * 16384, ldsB + 3 * 16384, aB, bB, [&] { STG(t2 + 3, 0, 1); });
  }
  // tail: t=NT-2 (buf0), t=NT-1 (buf1); drain 8 -> 4 -> 0
  phase_fn<8>(acc, ldsA + 0 * 16384, ldsB + 0 * 16384, aB, bB, [&] { STG(NT - 1, 1, 1); });
  phase_fn<4>(acc, ldsA + 1 * 16384, ldsB + 1 * 16384, aB, bB, [&] {});
  phase_fn<0>(acc, ldsA + 2 * 16384, ldsB + 2 * 16384, aB, bB, [&] {});
  phase_fn<0>(acc, ldsA + 3 * 16384, ldsB + 3 * 16384, aB, bB, [&] {});

  // epilogue: nf even = u, nf odd = v (same h cols) -> swiglu in-register
#pragma unroll
  for (int mf = 0; mf < 4; mf++) {
#pragma unroll
    for (int j = 0; j < 4; j++) {
      f32x4 uu = acc[mf][2 * j], vv = acc[mf][2 * j + 1];
      int hcol = nt * 128 + wc * 64 + j * 16 + l15;
#pragma unroll
      for (int rr = 0; rr < 4; rr++) {
        int r_out = row0 + wr * 64 + mf * 16 + g4 * 4 + rr;
        float xx = uu[rr];
        float hh = (xx / (1.f + __expf(-xx))) * vv[rr];
        h_buf[(size_t)r_out * H_DIM + hcol] = f2bf(hh);
      }
    }
  }
}

// ---------------- pass B: y = h*W3, weighted scatter-add; K-split 2 ----------------
__global__ __launch_bounds__(512, 2) void ffn2_kernel(
    const unsigned short* __restrict__ h_buf, const unsigned short* __restrict__ W3t,
    const int* __restrict__ pair_tok, const float* __restrict__ pair_w,
    const int* __restrict__ tile2e, const int* __restrict__ tile_row0,
    float* __restrict__ out) {
  extern __shared__ char lds[];
  char* ldsA = lds;
  char* ldsB = lds + 65536;
  const int NWG = MAXT * 8;    // 576, %8==0
  int orig = blockIdx.x;
  int wg = (orig & 7) * (NWG >> 3) + (orig >> 3);
  int f = wg >> 3;
  int r8 = wg & 7;
  int nt = r8 & 3, kseg = r8 >> 2;
  int e = tile2e[f];
  if (e < 0) return;
  int row0 = tile_row0[f];

  int tid = threadIdx.x;
  int w = tid >> 6, lane = tid & 63;
  int l15 = lane & 15, g4 = lane >> 4;
  int wr = w >> 1, wc = w & 1;

  int qs = (tid & 3) ^ ((tid >> 3) & 3);
  int rA = tid >> 2;
  const char* gA0 = (const char*)h_buf + (size_t)(row0 + rA) * 4096 + kseg * 2048 + qs * 16;
  const char* gA1 = (const char*)h_buf + (size_t)(row0 + rA + 128) * 4096 + kseg * 2048 + qs * 16;
  const char* W3e = (const char*)W3t + (size_t)e * 1024 * 4096;
  const char* gB0 = W3e + (size_t)(nt * 256 + rA) * 4096 + kseg * 2048 + qs * 16;
  const char* gB1 = W3e + (size_t)(nt * 256 + rA + 128) * 4096 + kseg * 2048 + qs * 16;

  auto STG = [&](int kt, int kh, int buf) {
    int off = kt * 128 + kh * 64;
    char* dA = ldsA + (buf * 2 + kh) * 16384 + w * 1024;
    char* dB = ldsB + (buf * 2 + kh) * 16384 + w * 1024;
    gload16(gA0 + off, dA);  gload16(gA1 + off, dA + 8192);
    gload16(gB0 + off, dB);  gload16(gB1 + off, dB + 8192);
  };

  int qr = g4 ^ ((lane >> 1) & 3);
  int aB = wr * 4096 + l15 * 64 + qr * 16;
  int bB = wc * 8192 + l15 * 64 + qr * 16;

  f32x4 acc[4][8];
#pragma unroll
  for (int i = 0; i < 4; i++)
#pragma unroll
    for (int j = 0; j < 8; j++) acc[i][j] = (f32x4){0.f, 0.f, 0.f, 0.f};

  STG(0, 0, 0); STG(0, 1, 0); STG(1, 0, 1);
  asm volatile("s_waitcnt vmcnt(8)" ::: "memory");
  __builtin_amdgcn_s_barrier();

  const int NT = 16;  // 1024 K per kseg / 64
#pragma unroll 1
  for (int t2 = 0; t2 < NT - 2; t2 += 2) {
    phase_fn<8>(acc, ldsA + 0 * 16384, ldsB + 0 * 16384, aB, bB, [&] { STG(t2 + 1, 1, 1); });
    phase_fn<8>(acc, ldsA + 1 * 16384, ldsB + 1 * 16384, aB, bB, [&] { STG(t2 + 2, 0, 0); });
    phase_fn<8>(acc, ldsA + 2 * 16384, ldsB + 2 * 16384, aB, bB, [&] { STG(t2 + 2, 1, 0); });
    phase_fn<8>(acc, ldsA + 3 * 16384, ldsB + 3 * 16384, aB, bB, [&] { STG(t2 + 3, 0, 1); });
  }
  phase_fn<8>(acc, ldsA + 0 * 16384, ldsB + 0 * 16384, aB, bB, [&] { STG(NT - 1, 1, 1); });
  phase_fn<4>(acc, ldsA + 1 * 16384, ldsB + 1 * 16384, aB, bB, [&] {});
  phase_fn<0>(acc, ldsA + 2 * 16384, ldsB + 2 * 16384, aB, bB, [&] {});
  phase_fn<0>(acc, ldsA + 3 * 16384, ldsB + 3 * 16384, aB, bB, [&] {});

#pragma unroll
  for (int mf = 0; mf < 4; mf++) {
#pragma unroll
    for (int rr = 0; rr < 4; rr++) {
      int pos = row0 + wr * 64 + mf * 16 + g4 * 4 + rr;
      int tok = pair_tok[pos];
      float wgt = pair_w[pos];
      float* orow = out + (size_t)tok * D_DIM + nt * 256 + wc * 128 + l15;
#pragma unroll
      for (int nf = 0; nf < 8; nf++)
        unsafeAtomicAdd(orow + nf * 16, acc[mf][nf][rr] * wgt);
    }
  }
}

// ---------------- launch ----------------
extern "C" void kernel_launch(void* const* d_in, const int* in_sizes, int n_in,
                              void* d_out, int out_size, void* d_ws, size_t ws_size,
                              hipStream_t stream) {
  const float* x  = (const float*)d_in[0];
  const float* Wg = (const float*)d_in[1];
  const float* W1 = (const float*)d_in[2];
  const float* W2 = (const float*)d_in[3];
  const float* W3 = (const float*)d_in[4];
  float* out = (float*)d_out;

  char* ws = (char*)d_ws;
  size_t off = 0;
  auto alloc = [&](size_t bytes) -> char* {
    char* p = ws + off; off += (bytes + 255) & ~(size_t)255; return p;
  };

  int*            cnt       = (int*)alloc(16 * 4);
  int*            poffs     = (int*)alloc(16 * 4);
  int*            run       = (int*)alloc(16 * 4);
  int*            tile2e    = (int*)alloc(80 * 4);
  int*            tile_row0 = (int*)alloc(80 * 4);
  int*            tok_e01   = (int*)alloc(T_TOKENS * 4);
  float*          tok_w     = (float*)alloc(T_TOKENS * 8);
  int*            pair_tok  = (int*)alloc(MAXP * 4);
  float*          pair_w    = (float*)alloc(MAXP * 4);
  unsigned short* xb        = (unsigned short*)alloc((size_t)T_TOKENS * D_DIM * 2);
  unsigned short* Bcat      = (unsigned short*)alloc((size_t)E_NUM * 4096 * 1024 * 2);
  unsigned short* W3t       = (unsigned short*)alloc((size_t)E_NUM * D_DIM * H_DIM * 2);
  unsigned short* h_buf     = (unsigned short*)alloc((size_t)MAXP * H_DIM * 2);

  hipFuncSetAttribute((const void*)ffn1_kernel, hipFuncAttributeMaxDynamicSharedMemorySize, 131072);
  hipFuncSetAttribute((const void*)ffn2_kernel, hipFuncAttributeMaxDynamicSharedMemorySize, 131072);

  hipMemsetAsync(cnt, 0, 16 * 4, stream);
  hipMemsetAsync(run, 0, 16 * 4, stream);
  hipMemsetAsync(pair_tok, 0, MAXP * 4, stream);
  hipMemsetAsync(pair_w, 0, MAXP * 4, stream);
  hipMemsetAsync(out, 0, (size_t)out_size * sizeof(float), stream);

  router_kernel<<<T_TOKENS / 4, 256, 0, stream>>>(x, Wg, cnt, tok_e01, tok_w);
  scan_kernel<<<1, 64, 0, stream>>>(cnt, poffs, tile2e, tile_row0);
  assign_kernel<<<T_TOKENS / 256, 256, 0, stream>>>(tok_e01, tok_w, poffs, run, pair_tok, pair_w);
  cast_x_kernel<<<(T_TOKENS * D_DIM / 8) / 256, 256, 0, stream>>>(x, xb);
  dim3 tb(32, 8);
  cast_transpose_cat_kernel<<<dim3(H_DIM / 32, D_DIM / 32, E_NUM), tb, 0, stream>>>(W1, Bcat, 0);
  cast_transpose_cat_kernel<<<dim3(H_DIM / 32, D_DIM / 32, E_NUM), tb, 0, stream>>>(W2, Bcat, 1);
  cast_transpose_kernel<<<dim3(D_DIM / 32, H_DIM / 32, E_NUM), tb, 0, stream>>>(W3, W3t, H_DIM, D_DIM);

  ffn1_kernel<<<dim3(MAXT * 16), 512, 131072, stream>>>(xb, Bcat, h_buf, pair_tok, tile2e, tile_row0);
  ffn2_kernel<<<dim3(MAXT * 8), 512, 131072, stream>>>(h_buf, W3t, pair_tok, pair_w, tile2e, tile_row0, out);
}

// Round 4
// 654.284 us; speedup vs baseline: 1.3279x; 1.3279x over previous
//
#include <hip/hip_runtime.h>
#include <stdint.h>

#define T_TOKENS 8192
#define D_DIM 1024
#define H_DIM 2048
#define E_NUM 8
#define MAXP 18432         // pairs padded to 256/expert
#define MAXT 72            // max sum of per-expert ceil(cnt/256)

typedef __attribute__((ext_vector_type(8))) short short8;
typedef __attribute__((ext_vector_type(4))) float f32x4;
typedef __attribute__((ext_vector_type(8))) unsigned short u16x8;

__device__ __forceinline__ unsigned short f2bf(float f) {
  union { float f; uint32_t u; } v; v.f = f;
  uint32_t r = (v.u + 0x7fffu + ((v.u >> 16) & 1u)) >> 16;
  return (unsigned short)r;
}

__device__ __forceinline__ float bf2f(unsigned short u) {
  union { uint32_t u; float f; } v; v.u = ((uint32_t)u) << 16;
  return v.f;
}

__device__ __forceinline__ void gload16(const void* g, void* l) {
  __builtin_amdgcn_global_load_lds((const __attribute__((address_space(1))) void*)g,
                                   (__attribute__((address_space(3))) void*)l, 16, 0, 0);
}

// ---------------- router: logits (f64 accum), top-2, softmax, counts ----------------
__global__ void router_kernel(const float* __restrict__ x, const float* __restrict__ Wg,
                              int* __restrict__ cnt, int* __restrict__ tok_e01,
                              float* __restrict__ tok_w) {
  __shared__ float wgT[E_NUM * D_DIM];
  int tid = threadIdx.x;
  for (int i = tid; i < D_DIM * E_NUM; i += 256) {
    int d = i >> 3, e = i & 7;
    wgT[e * D_DIM + d] = Wg[i];
  }
  __syncthreads();
  int wid = tid >> 6, lane = tid & 63;
  int t = blockIdx.x * 4 + wid;
  const float* xr = x + (size_t)t * D_DIM;
  double acc[E_NUM];
#pragma unroll
  for (int e = 0; e < E_NUM; e++) acc[e] = 0.0;
  for (int i = 0; i < D_DIM / 64; i++) {
    double xv = (double)xr[i * 64 + lane];
#pragma unroll
    for (int e = 0; e < E_NUM; e++) acc[e] += xv * (double)wgT[e * D_DIM + i * 64 + lane];
  }
#pragma unroll
  for (int e = 0; e < E_NUM; e++) {
    double v = acc[e];
#pragma unroll
    for (int off = 32; off >= 1; off >>= 1) v += __shfl_xor(v, off);
    acc[e] = v;
  }
  if (lane == 0) {
    int e0 = 0; double l0 = acc[0];
#pragma unroll
    for (int e = 1; e < E_NUM; e++) if (acc[e] > l0) { l0 = acc[e]; e0 = e; }
    int e1 = -1; double l1 = -1e300;
#pragma unroll
    for (int e = 0; e < E_NUM; e++) if (e != e0 && acc[e] > l1) { l1 = acc[e]; e1 = e; }
    float z1 = expf((float)(l1 - l0));
    float w0 = 1.f / (1.f + z1);
    float w1 = z1 * w0;
    tok_e01[t] = e0 | (e1 << 8);
    tok_w[2 * t] = w0; tok_w[2 * t + 1] = w1;
    atomicAdd(&cnt[e0], 1);
    atomicAdd(&cnt[e1], 1);
  }
}

// 256-aligned per-expert segments + static tile table
__global__ void scan_kernel(const int* __restrict__ cnt, int* __restrict__ poffs,
                            int* __restrict__ tile2e, int* __restrict__ tile_row0) {
  if (threadIdx.x == 0) {
    int po = 0, tf = 0;
    for (int e = 0; e < E_NUM; e++) {
      poffs[e] = po;
      int nt = (cnt[e] + 255) >> 8;
      for (int i = 0; i < nt; i++) { tile2e[tf] = e; tile_row0[tf] = po + i * 256; tf++; }
      po += nt << 8;
    }
    for (; tf < MAXT; tf++) { tile2e[tf] = -1; tile_row0[tf] = 0; }
  }
}

__global__ void assign_kernel(const int* __restrict__ tok_e01, const float* __restrict__ tok_w,
                              const int* __restrict__ poffs, int* __restrict__ run,
                              int* __restrict__ pair_tok, int2* __restrict__ tok_pos) {
  int t = blockIdx.x * 256 + threadIdx.x;
  if (t >= T_TOKENS) return;
  int p = tok_e01[t];
  int e0 = p & 255, e1 = (p >> 8) & 255;
  int pos0 = poffs[e0] + atomicAdd(&run[e0], 1);
  pair_tok[pos0] = t;
  int pos1 = poffs[e1] + atomicAdd(&run[e1], 1);
  pair_tok[pos1] = t;
  tok_pos[t] = make_int2(pos0, pos1);
}

// ---------------- casts ----------------
__global__ void cast_x_kernel(const float* __restrict__ x, unsigned short* __restrict__ xb) {
  int i = blockIdx.x * 256 + threadIdx.x;
  const float4* xp = (const float4*)x;
  float4 a = xp[2 * i], b = xp[2 * i + 1];
  u16x8 r;
  r[0] = f2bf(a.x); r[1] = f2bf(a.y); r[2] = f2bf(a.z); r[3] = f2bf(a.w);
  r[4] = f2bf(b.x); r[5] = f2bf(b.y); r[6] = f2bf(b.z); r[7] = f2bf(b.w);
  *(u16x8*)(xb + (size_t)i * 8) = r;
}

// W3: [E][H][D] f32 -> [E][D][H] bf16 (N-major, K contiguous)
__global__ void cast_transpose_kernel(const float* __restrict__ in, unsigned short* __restrict__ out,
                                      int R, int C) {
  __shared__ float tile[32][33];
  int e = blockIdx.z;
  const float* src = in + (size_t)e * R * C;
  unsigned short* dst = out + (size_t)e * R * C;
  int c0 = blockIdx.x * 32, r0 = blockIdx.y * 32;
  int tx = threadIdx.x, ty = threadIdx.y;
#pragma unroll
  for (int i = 0; i < 4; i++)
    tile[ty + i * 8][tx] = src[(size_t)(r0 + ty + i * 8) * C + c0 + tx];
  __syncthreads();
#pragma unroll
  for (int i = 0; i < 4; i++)
    dst[(size_t)(c0 + ty + i * 8) * R + r0 + tx] = f2bf(tile[tx][ty + i * 8]);
}

// W1/W2: [E][D][H] f32 -> Bcat [E][4096][1024] bf16, 16-col interleave (u / v per 32-row group)
__global__ void cast_transpose_cat_kernel(const float* __restrict__ in, unsigned short* __restrict__ Bcat,
                                          int isV) {
  __shared__ float tile[32][33];
  int e = blockIdx.z;
  const float* src = in + (size_t)e * D_DIM * H_DIM;
  unsigned short* dst = Bcat + (size_t)e * 4096 * 1024;
  int c0 = blockIdx.x * 32, r0 = blockIdx.y * 32;
  int tx = threadIdx.x, ty = threadIdx.y;
#pragma unroll
  for (int i = 0; i < 4; i++)
    tile[ty + i * 8][tx] = src[(size_t)(r0 + ty + i * 8) * H_DIM + c0 + tx];
  __syncthreads();
#pragma unroll
  for (int i = 0; i < 4; i++) {
    int n = c0 + ty + i * 8;
    int nr = ((n >> 4) << 5) + (n & 15) + isV * 16;
    dst[(size_t)nr * 1024 + r0 + tx] = f2bf(tile[tx][ty + i * 8]);
  }
}

// ---------------- pass A: fused h = swish(x*W1)*(x*W2) via Bcat. 128x128, BK=32, 4 waves ----------------
__global__ __launch_bounds__(256, 3) void ffn1_kernel(
    const unsigned short* __restrict__ xb, const unsigned short* __restrict__ Bcat,
    unsigned short* __restrict__ h_buf,
    const int* __restrict__ pair_tok, const int* __restrict__ tile2e,
    const int* __restrict__ tile_row0) {
  const int NWG = MAXT * 32;  // 2304, %8==0
  int orig = blockIdx.x;
  int wg = (orig & 7) * (NWG >> 3) + (orig >> 3);
  int f = wg >> 5, nt = wg & 31;          // 32 N-tiles (N=4096)
  int e = tile2e[f];
  if (e < 0) return;
  int row0 = tile_row0[f];
  int mrow0 = (wg & 1) ? 128 : 0;         // which 128-half of the 256-row segment
  // tile covers rows row0 + mrow0 .. +127 : split 256-row segments into two 128 M-tiles
  // remap: use f covering 256 rows, nt covers N; M halves alternate by nt parity would skew;
  // instead: each (f, nt) block handles BOTH 128-row halves? No - keep 128 rows: encode half in nt bit.
  // nt in [0,32): actual N-tile = nt; M-half chosen by an extra grid factor below.
  int half = blockIdx.y;                  // 0 or 1
  row0 += half * 128;

  __shared__ alignas(16) char ldsA[2][8192];
  __shared__ alignas(16) char ldsB[2][8192];

  int tid = threadIdx.x, w = tid >> 6, lane = tid & 63;
  int l15 = lane & 15, g4 = lane >> 4;
  int wr = w >> 1, wc = w & 1;

  int r = tid >> 2;                        // 0..63
  int qs = (tid & 3) ^ ((r >> 1) & 3);     // pre-swizzled source chunk
  int tok0 = pair_tok[row0 + r];
  int tok1 = pair_tok[row0 + r + 64];
  const char* gA0 = (const char*)xb + (size_t)tok0 * 2048 + qs * 16;
  const char* gA1 = (const char*)xb + (size_t)tok1 * 2048 + qs * 16;
  const char* Bce = (const char*)Bcat + (size_t)e * 4096 * 2048;
  const char* gB0 = Bce + (size_t)(nt * 128 + r) * 2048 + qs * 16;
  const char* gB1 = Bce + (size_t)(nt * 128 + r + 64) * 2048 + qs * 16;

  auto STG = [&](int buf, int ks) {
    int ko = ks * 64;
    char* dA = &ldsA[buf][w * 1024];
    char* dB = &ldsB[buf][w * 1024];
    gload16(gA0 + ko, dA); gload16(gA1 + ko, dA + 4096);
    gload16(gB0 + ko, dB); gload16(gB1 + ko, dB + 4096);
  };

  int qr = g4 ^ ((l15 >> 1) & 3);          // swizzled read chunk
  int aoff[4], boff[4];
#pragma unroll
  for (int i = 0; i < 4; i++) {
    aoff[i] = (wr * 64 + i * 16 + l15) * 64 + qr * 16;
    boff[i] = (wc * 64 + i * 16 + l15) * 64 + qr * 16;
  }

  f32x4 acc[4][4];
#pragma unroll
  for (int i = 0; i < 4; i++)
#pragma unroll
    for (int j = 0; j < 4; j++) acc[i][j] = (f32x4){0.f, 0.f, 0.f, 0.f};

  const int NK = 32;
  STG(0, 0);
  __syncthreads();
#pragma unroll 1
  for (int ks = 0; ks < NK; ks++) {
    int cur = ks & 1;
    if (ks + 1 < NK) STG(cur ^ 1, ks + 1);
    short8 af[4], bf[4];
#pragma unroll
    for (int i = 0; i < 4; i++) {
      af[i] = *(const short8*)(&ldsA[cur][aoff[i]]);
      bf[i] = *(const short8*)(&ldsB[cur][boff[i]]);
    }
#pragma unroll
    for (int i = 0; i < 4; i++)
#pragma unroll
      for (int j = 0; j < 4; j++)
        acc[i][j] = __builtin_amdgcn_mfma_f32_16x16x32_bf16(af[i], bf[j], acc[i][j], 0, 0, 0);
    if (ks + 1 < NK) __syncthreads();
  }

  // epilogue: nf even = u, nf odd = v for the same h-column group
#pragma unroll
  for (int mf = 0; mf < 4; mf++) {
#pragma unroll
    for (int p = 0; p < 2; p++) {
      f32x4 uu = acc[mf][2 * p], vv = acc[mf][2 * p + 1];
      int n = (nt * 4 + wc * 2 + p) * 16 + l15;
#pragma unroll
      for (int rr = 0; rr < 4; rr++) {
        int r_out = row0 + wr * 64 + mf * 16 + g4 * 4 + rr;
        float xx = uu[rr];
        float hh = (xx / (1.f + __expf(-xx))) * vv[rr];
        h_buf[(size_t)r_out * H_DIM + n] = f2bf(hh);
      }
    }
  }
}

// ---------------- pass B: y = h*W3 -> y_buf (bf16, unweighted). 128x128, BK=32, 4 waves ----------------
__global__ __launch_bounds__(256, 3) void ffn2_kernel(
    const unsigned short* __restrict__ h_buf, const unsigned short* __restrict__ W3t,
    unsigned short* __restrict__ y_buf,
    const int* __restrict__ tile2e, const int* __restrict__ tile_row0) {
  const int NWG = MAXT * 8;   // 576, %8==0
  int orig = blockIdx.x;
  int wg = (orig & 7) * (NWG >> 3) + (orig >> 3);
  int f = wg >> 3, nt = wg & 7;           // 8 N-tiles (N=1024)
  int e = tile2e[f];
  if (e < 0) return;
  int row0 = tile_row0[f] + blockIdx.y * 128;

  __shared__ alignas(16) char ldsA[2][8192];
  __shared__ alignas(16) char ldsB[2][8192];

  int tid = threadIdx.x, w = tid >> 6, lane = tid & 63;
  int l15 = lane & 15, g4 = lane >> 4;
  int wr = w >> 1, wc = w & 1;

  int r = tid >> 2;
  int qs = (tid & 3) ^ ((r >> 1) & 3);
  const char* gA0 = (const char*)h_buf + (size_t)(row0 + r) * 4096 + qs * 16;
  const char* gA1 = (const char*)h_buf + (size_t)(row0 + r + 64) * 4096 + qs * 16;
  const char* W3e = (const char*)W3t + (size_t)e * 1024 * 4096;
  const char* gB0 = W3e + (size_t)(nt * 128 + r) * 4096 + qs * 16;
  const char* gB1 = W3e + (size_t)(nt * 128 + r + 64) * 4096 + qs * 16;

  auto STG = [&](int buf, int ks) {
    int ko = ks * 64;
    char* dA = &ldsA[buf][w * 1024];
    char* dB = &ldsB[buf][w * 1024];
    gload16(gA0 + ko, dA); gload16(gA1 + ko, dA + 4096);
    gload16(gB0 + ko, dB); gload16(gB1 + ko, dB + 4096);
  };

  int qr = g4 ^ ((l15 >> 1) & 3);
  int aoff[4], boff[4];
#pragma unroll
  for (int i = 0; i < 4; i++) {
    aoff[i] = (wr * 64 + i * 16 + l15) * 64 + qr * 16;
    boff[i] = (wc * 64 + i * 16 + l15) * 64 + qr * 16;
  }

  f32x4 acc[4][4];
#pragma unroll
  for (int i = 0; i < 4; i++)
#pragma unroll
    for (int j = 0; j < 4; j++) acc[i][j] = (f32x4){0.f, 0.f, 0.f, 0.f};

  const int NK = 64;
  STG(0, 0);
  __syncthreads();
#pragma unroll 1
  for (int ks = 0; ks < NK; ks++) {
    int cur = ks & 1;
    if (ks + 1 < NK) STG(cur ^ 1, ks + 1);
    short8 af[4], bf[4];
#pragma unroll
    for (int i = 0; i < 4; i++) {
      af[i] = *(const short8*)(&ldsA[cur][aoff[i]]);
      bf[i] = *(const short8*)(&ldsB[cur][boff[i]]);
    }
#pragma unroll
    for (int i = 0; i < 4; i++)
#pragma unroll
      for (int j = 0; j < 4; j++)
        acc[i][j] = __builtin_amdgcn_mfma_f32_16x16x32_bf16(af[i], bf[j], acc[i][j], 0, 0, 0);
    if (ks + 1 < NK) __syncthreads();
  }

#pragma unroll
  for (int mf = 0; mf < 4; mf++) {
#pragma unroll
    for (int nf = 0; nf < 4; nf++) {
      int col = nt * 128 + wc * 64 + nf * 16 + l15;
#pragma unroll
      for (int rr = 0; rr < 4; rr++) {
        int pos = row0 + wr * 64 + mf * 16 + g4 * 4 + rr;
        y_buf[(size_t)pos * D_DIM + col] = f2bf(acc[mf][nf][rr]);
      }
    }
  }
}

// ---------------- combine: out[t] = w0*y[pos0] + w1*y[pos1] ----------------
__global__ void combine_kernel(const unsigned short* __restrict__ y_buf,
                               const int2* __restrict__ tok_pos, const float* __restrict__ tok_w,
                               float* __restrict__ out) {
  int t = blockIdx.x * 2 + (threadIdx.x >> 7);
  int c = (threadIdx.x & 127) * 8;
  int2 p = tok_pos[t];
  float w0 = tok_w[2 * t], w1 = tok_w[2 * t + 1];
  u16x8 a = *(const u16x8*)(y_buf + (size_t)p.x * D_DIM + c);
  u16x8 b = *(const u16x8*)(y_buf + (size_t)p.y * D_DIM + c);
  float o[8];
#pragma unroll
  for (int k = 0; k < 8; k++) o[k] = w0 * bf2f(a[k]) + w1 * bf2f(b[k]);
  float4* op = (float4*)(out + (size_t)t * D_DIM + c);
  op[0] = make_float4(o[0], o[1], o[2], o[3]);
  op[1] = make_float4(o[4], o[5], o[6], o[7]);
}

// ---------------- launch ----------------
extern "C" void kernel_launch(void* const* d_in, const int* in_sizes, int n_in,
                              void* d_out, int out_size, void* d_ws, size_t ws_size,
                              hipStream_t stream) {
  const float* x  = (const float*)d_in[0];
  const float* Wg = (const float*)d_in[1];
  const float* W1 = (const float*)d_in[2];
  const float* W2 = (const float*)d_in[3];
  const float* W3 = (const float*)d_in[4];
  float* out = (float*)d_out;

  char* ws = (char*)d_ws;
  size_t off = 0;
  auto alloc = [&](size_t bytes) -> char* {
    char* p = ws + off; off += (bytes + 255) & ~(size_t)255; return p;
  };

  int*            cnt       = (int*)alloc(16 * 4);
  int*            poffs     = (int*)alloc(16 * 4);
  int*            run       = (int*)alloc(16 * 4);
  int*            tile2e    = (int*)alloc(80 * 4);
  int*            tile_row0 = (int*)alloc(80 * 4);
  int*            tok_e01   = (int*)alloc(T_TOKENS * 4);
  float*          tok_w     = (float*)alloc(T_TOKENS * 8);
  int2*           tok_pos   = (int2*)alloc(T_TOKENS * 8);
  int*            pair_tok  = (int*)alloc(MAXP * 4);
  unsigned short* xb        = (unsigned short*)alloc((size_t)T_TOKENS * D_DIM * 2);
  unsigned short* Bcat      = (unsigned short*)alloc((size_t)E_NUM * 4096 * 1024 * 2);
  unsigned short* W3t       = (unsigned short*)alloc((size_t)E_NUM * D_DIM * H_DIM * 2);
  unsigned short* h_buf     = (unsigned short*)alloc((size_t)MAXP * H_DIM * 2);
  unsigned short* y_buf     = Bcat;  // alias: Bcat is dead once ffn1 completes (same stream)

  hipMemsetAsync(cnt, 0, 16 * 4, stream);
  hipMemsetAsync(run, 0, 16 * 4, stream);
  hipMemsetAsync(pair_tok, 0, MAXP * 4, stream);

  router_kernel<<<T_TOKENS / 4, 256, 0, stream>>>(x, Wg, cnt, tok_e01, tok_w);
  scan_kernel<<<1, 64, 0, stream>>>(cnt, poffs, tile2e, tile_row0);
  assign_kernel<<<T_TOKENS / 256, 256, 0, stream>>>(tok_e01, tok_w, poffs, run, pair_tok, tok_pos);
  cast_x_kernel<<<(T_TOKENS * D_DIM / 8) / 256, 256, 0, stream>>>(x, xb);
  dim3 tb(32, 8);
  cast_transpose_cat_kernel<<<dim3(H_DIM / 32, D_DIM / 32, E_NUM), tb, 0, stream>>>(W1, Bcat, 0);
  cast_transpose_cat_kernel<<<dim3(H_DIM / 32, D_DIM / 32, E_NUM), tb, 0, stream>>>(W2, Bcat, 1);
  cast_transpose_kernel<<<dim3(D_DIM / 32, H_DIM / 32, E_NUM), tb, 0, stream>>>(W3, W3t, H_DIM, D_DIM);

  ffn1_kernel<<<dim3(MAXT * 32, 2), 256, 0, stream>>>(xb, Bcat, h_buf, pair_tok, tile2e, tile_row0);
  ffn2_kernel<<<dim3(MAXT * 8, 2), 256, 0, stream>>>(h_buf, W3t, y_buf, tile2e, tile_row0);
  combine_kernel<<<T_TOKENS / 2, 256, 0, stream>>>(y_buf, tok_pos, tok_w, out);
}

// Round 5
// 627.477 us; speedup vs baseline: 1.3846x; 1.0427x over previous
//
#include <hip/hip_runtime.h>
#include <stdint.h>

#define T_TOKENS 8192
#define D_DIM 1024
#define H_DIM 2048
#define E_NUM 8
#define MAXP 18432         // pairs padded to 256/expert
#define MAXT 72            // max sum of per-expert ceil(cnt/256)

typedef __attribute__((ext_vector_type(8))) short short8;
typedef __attribute__((ext_vector_type(4))) float f32x4;
typedef __attribute__((ext_vector_type(8))) unsigned short u16x8;

__device__ __forceinline__ unsigned short f2bf(float f) {
  union { float f; uint32_t u; } v; v.f = f;
  uint32_t r = (v.u + 0x7fffu + ((v.u >> 16) & 1u)) >> 16;
  return (unsigned short)r;
}

__device__ __forceinline__ float bf2f(unsigned short u) {
  union { uint32_t u; float f; } v; v.u = ((uint32_t)u) << 16;
  return v.f;
}

__device__ __forceinline__ void gload16(const void* g, void* l) {
  __builtin_amdgcn_global_load_lds((const __attribute__((address_space(1))) void*)g,
                                   (__attribute__((address_space(3))) void*)l, 16, 0, 0);
}

// ---------------- router: logits (f64 accum), top-2, softmax, counts ----------------
__global__ void router_kernel(const float* __restrict__ x, const float* __restrict__ Wg,
                              int* __restrict__ cnt, int* __restrict__ tok_e01,
                              float* __restrict__ tok_w) {
  __shared__ float wgT[E_NUM * D_DIM];
  int tid = threadIdx.x;
  for (int i = tid; i < D_DIM * E_NUM; i += 256) {
    int d = i >> 3, e = i & 7;
    wgT[e * D_DIM + d] = Wg[i];
  }
  __syncthreads();
  int wid = tid >> 6, lane = tid & 63;
  int t = blockIdx.x * 4 + wid;
  const float* xr = x + (size_t)t * D_DIM;
  double acc[E_NUM];
#pragma unroll
  for (int e = 0; e < E_NUM; e++) acc[e] = 0.0;
  for (int i = 0; i < D_DIM / 64; i++) {
    double xv = (double)xr[i * 64 + lane];
#pragma unroll
    for (int e = 0; e < E_NUM; e++) acc[e] += xv * (double)wgT[e * D_DIM + i * 64 + lane];
  }
#pragma unroll
  for (int e = 0; e < E_NUM; e++) {
    double v = acc[e];
#pragma unroll
    for (int off = 32; off >= 1; off >>= 1) v += __shfl_xor(v, off);
    acc[e] = v;
  }
  if (lane == 0) {
    int e0 = 0; double l0 = acc[0];
#pragma unroll
    for (int e = 1; e < E_NUM; e++) if (acc[e] > l0) { l0 = acc[e]; e0 = e; }
    int e1 = -1; double l1 = -1e300;
#pragma unroll
    for (int e = 0; e < E_NUM; e++) if (e != e0 && acc[e] > l1) { l1 = acc[e]; e1 = e; }
    float z1 = expf((float)(l1 - l0));
    float w0 = 1.f / (1.f + z1);
    float w1 = z1 * w0;
    tok_e01[t] = e0 | (e1 << 8);
    tok_w[2 * t] = w0; tok_w[2 * t + 1] = w1;
    atomicAdd(&cnt[e0], 1);
    atomicAdd(&cnt[e1], 1);
  }
}

// 256-aligned per-expert segments + static tile table
__global__ void scan_kernel(const int* __restrict__ cnt, int* __restrict__ poffs,
                            int* __restrict__ tile2e, int* __restrict__ tile_row0) {
  if (threadIdx.x == 0) {
    int po = 0, tf = 0;
    for (int e = 0; e < E_NUM; e++) {
      poffs[e] = po;
      int nt = (cnt[e] + 255) >> 8;
      for (int i = 0; i < nt; i++) { tile2e[tf] = e; tile_row0[tf] = po + i * 256; tf++; }
      po += nt << 8;
    }
    for (; tf < MAXT; tf++) { tile2e[tf] = -1; tile_row0[tf] = 0; }
  }
}

__global__ void assign_kernel(const int* __restrict__ tok_e01, const float* __restrict__ tok_w,
                              const int* __restrict__ poffs, int* __restrict__ run,
                              int* __restrict__ pair_tok, int2* __restrict__ tok_pos) {
  int t = blockIdx.x * 256 + threadIdx.x;
  if (t >= T_TOKENS) return;
  int p = tok_e01[t];
  int e0 = p & 255, e1 = (p >> 8) & 255;
  int pos0 = poffs[e0] + atomicAdd(&run[e0], 1);
  pair_tok[pos0] = t;
  int pos1 = poffs[e1] + atomicAdd(&run[e1], 1);
  pair_tok[pos1] = t;
  tok_pos[t] = make_int2(pos0, pos1);
}

// ---------------- casts ----------------
__global__ void cast_x_kernel(const float* __restrict__ x, unsigned short* __restrict__ xb) {
  int i = blockIdx.x * 256 + threadIdx.x;
  const float4* xp = (const float4*)x;
  float4 a = xp[2 * i], b = xp[2 * i + 1];
  u16x8 r;
  r[0] = f2bf(a.x); r[1] = f2bf(a.y); r[2] = f2bf(a.z); r[3] = f2bf(a.w);
  r[4] = f2bf(b.x); r[5] = f2bf(b.y); r[6] = f2bf(b.z); r[7] = f2bf(b.w);
  *(u16x8*)(xb + (size_t)i * 8) = r;
}

// W3: [E][H][D] f32 -> [E][D][H] bf16 (N-major, K contiguous)
__global__ void cast_transpose_kernel(const float* __restrict__ in, unsigned short* __restrict__ out,
                                      int R, int C) {
  __shared__ float tile[32][33];
  int e = blockIdx.z;
  const float* src = in + (size_t)e * R * C;
  unsigned short* dst = out + (size_t)e * R * C;
  int c0 = blockIdx.x * 32, r0 = blockIdx.y * 32;
  int tx = threadIdx.x, ty = threadIdx.y;
#pragma unroll
  for (int i = 0; i < 4; i++)
    tile[ty + i * 8][tx] = src[(size_t)(r0 + ty + i * 8) * C + c0 + tx];
  __syncthreads();
#pragma unroll
  for (int i = 0; i < 4; i++)
    dst[(size_t)(c0 + ty + i * 8) * R + r0 + tx] = f2bf(tile[tx][ty + i * 8]);
}

// W1/W2: [E][D][H] f32 -> Bcat [E][4096][1024] bf16, 16-col interleave (u / v per 32-row group)
__global__ void cast_transpose_cat_kernel(const float* __restrict__ in, unsigned short* __restrict__ Bcat,
                                          int isV) {
  __shared__ float tile[32][33];
  int e = blockIdx.z;
  const float* src = in + (size_t)e * D_DIM * H_DIM;
  unsigned short* dst = Bcat + (size_t)e * 4096 * 1024;
  int c0 = blockIdx.x * 32, r0 = blockIdx.y * 32;
  int tx = threadIdx.x, ty = threadIdx.y;
#pragma unroll
  for (int i = 0; i < 4; i++)
    tile[ty + i * 8][tx] = src[(size_t)(r0 + ty + i * 8) * H_DIM + c0 + tx];
  __syncthreads();
#pragma unroll
  for (int i = 0; i < 4; i++) {
    int n = c0 + ty + i * 8;
    int nr = ((n >> 4) << 5) + (n & 15) + isV * 16;
    dst[(size_t)nr * 1024 + r0 + tx] = f2bf(tile[tx][ty + i * 8]);
  }
}

// ---------------- pass A: 8-phase-class 256x256 deep pipeline (m201-style) ----------------
// BM=BN=256, BK=64, NT=16. 8 waves (2M x 4N), per-wave C = 128x64 (acc[8][4]).
// LDS 128KB dynamic: A: [2buf][2half][128r][128B] @0; B same @65536.
// Swizzle: 16B chunk c at row r holds k-chunk c^(r&7) (both-sides, 2-way = free).
// 4 phases/K-tile, 16 MFMA each; stage 1 half-tile/phase; vmcnt(4) once per tile.
__global__ __launch_bounds__(512, 2) void ffn1_kernel(
    const unsigned short* __restrict__ xb, const unsigned short* __restrict__ Bcat,
    unsigned short* __restrict__ h_buf,
    const int* __restrict__ pair_tok, const int* __restrict__ tile2e,
    const int* __restrict__ tile_row0) {
  extern __shared__ char lds[];
  char* ldsB = lds + 65536;
  const int NWG = MAXT * 16;  // 1152, %8==0
  int orig = blockIdx.x;
  int wg = (orig & 7) * (NWG >> 3) + (orig >> 3);
  int f = wg >> 4, nt = wg & 15;
  int e = tile2e[f];
  if (e < 0) return;
  int row0 = tile_row0[f];

  int tid = threadIdx.x;
  int w = tid >> 6, lane = tid & 63;
  int l15 = lane & 15, g4 = lane >> 4;
  int wr = w >> 2, wn = w & 3;

  // ---- staging addresses: slot s = w*64+lane (+512 for j=1); row = s>>3, chunk = s&7 ----
  int s0 = w * 64 + lane;
  int r0_ = s0 >> 3, c0_ = s0 & 7;
  int kc = c0_ ^ (r0_ & 7);          // src k-chunk (same for j=1: (r0_+64)&7 == r0_&7)
  const char* gA[2][2];
  const char* gB[2][2];
  const char* Bce = (const char*)Bcat + (size_t)e * 4096 * 2048;
#pragma unroll
  for (int h = 0; h < 2; h++) {
    int tokA0 = pair_tok[row0 + h * 128 + r0_];
    int tokA1 = pair_tok[row0 + h * 128 + r0_ + 64];
    gA[h][0] = (const char*)xb + (size_t)tokA0 * 2048 + kc * 16;
    gA[h][1] = (const char*)xb + (size_t)tokA1 * 2048 + kc * 16;
    gB[h][0] = Bce + (size_t)(nt * 256 + h * 128 + r0_) * 2048 + kc * 16;
    gB[h][1] = Bce + (size_t)(nt * 256 + h * 128 + r0_ + 64) * 2048 + kc * 16;
  }

  auto STG_A = [&](int kt, int h, int buf) {
    char* d = lds + buf * 32768 + h * 16384 + w * 1024;
    gload16(gA[h][0] + kt * 128, d);
    gload16(gA[h][1] + kt * 128, d + 8192);
  };
  auto STG_B = [&](int kt, int h, int buf) {
    char* d = ldsB + buf * 32768 + h * 16384 + w * 1024;
    gload16(gB[h][0] + kt * 128, d);
    gload16(gB[h][1] + kt * 128, d + 8192);
  };

  // ---- fragment read offsets (swizzled): chunk(ks) = cbase ^ (ks<<6) ----
  int sw = l15 & 7;
  int cbase = (sw >> 2) * 64 + ((g4 ^ (sw & 3)) * 16);
  int aRow = wr * 16384 + l15 * 128;          // half = wr
  int bRow = 65536 + wn * 8192 + l15 * 128;   // wn*8192 covers half+subrange

  f32x4 acc[8][4];
#pragma unroll
  for (int i = 0; i < 8; i++)
#pragma unroll
    for (int j = 0; j < 4; j++) acc[i][j] = (f32x4){0.f, 0.f, 0.f, 0.f};

  short8 a[4][2], blo[2][2], bhi[2][2];
  auto RD_A = [&](int mq, int buf) {
    const char* base = lds + buf * 32768 + aRow + mq * 8192;
#pragma unroll
    for (int m2 = 0; m2 < 4; m2++)
#pragma unroll
      for (int ks = 0; ks < 2; ks++)
        a[m2][ks] = *(const short8*)(base + m2 * 2048 + (cbase ^ (ks << 6)));
  };
  auto RD_B = [&](short8 (&b)[2][2], int nq, int buf) {
    const char* base = lds + buf * 32768 + bRow + nq * 4096;
#pragma unroll
    for (int n2 = 0; n2 < 2; n2++)
#pragma unroll
      for (int ks = 0; ks < 2; ks++)
        b[n2][ks] = *(const short8*)(base + n2 * 2048 + (cbase ^ (ks << 6)));
  };
  auto MM = [&](int mq, short8 (&b)[2][2], int nq) {
    __builtin_amdgcn_s_setprio(1);
#pragma unroll
    for (int m2 = 0; m2 < 4; m2++)
#pragma unroll
      for (int n2 = 0; n2 < 2; n2++)
#pragma unroll
        for (int ks = 0; ks < 2; ks++)
          acc[mq * 4 + m2][nq * 2 + n2] = __builtin_amdgcn_mfma_f32_16x16x32_bf16(
              a[m2][ks], b[n2][ks], acc[mq * 4 + m2][nq * 2 + n2], 0, 0, 0);
    __builtin_amdgcn_s_setprio(0);
  };

  // prologue: tile0 all 4 halves -> buf0; tile1 B-h0, A-h0 -> buf1
  STG_A(0, 0, 0); STG_A(0, 1, 0); STG_B(0, 0, 0); STG_B(0, 1, 0);
  STG_B(1, 0, 1); STG_A(1, 0, 1);
  asm volatile("s_waitcnt vmcnt(4)" ::: "memory");
  __builtin_amdgcn_s_barrier();
  asm volatile("" ::: "memory");

  const int NT = 16;
#pragma unroll 1
  for (int kt = 0; kt < NT; kt++) {
    int buf = kt & 1;
    // P1: read A-lo + B-lo; stage A(kt+1,h1)->buf^1
    RD_A(0, buf); RD_B(blo, 0, buf);
    if (kt + 1 < NT) STG_A(kt + 1, 1, buf ^ 1);
    __builtin_amdgcn_s_barrier();
    asm volatile("" ::: "memory");
    MM(0, blo, 0);
    __builtin_amdgcn_s_barrier();
    asm volatile("" ::: "memory");
    // P2: read B-hi; stage B(kt+1,h1)->buf^1
    RD_B(bhi, 1, buf);
    if (kt + 1 < NT) STG_B(kt + 1, 1, buf ^ 1);
    __builtin_amdgcn_s_barrier();
    asm volatile("" ::: "memory");
    MM(0, bhi, 1);
    __builtin_amdgcn_s_barrier();
    asm volatile("" ::: "memory");
    // P3: read A-hi; stage B(kt+2,h0)->buf (B-h0 reads finished at P2)
    RD_A(1, buf);
    if (kt + 2 < NT) STG_B(kt + 2, 0, buf);
    __builtin_amdgcn_s_barrier();
    asm volatile("" ::: "memory");
    MM(1, bhi, 1);
    __builtin_amdgcn_s_barrier();
    asm volatile("" ::: "memory");
    // P4: no reads (uses held A-hi, B-lo); stage A(kt+2,h0)->buf; per-tile checkpoint
    if (kt + 2 < NT) STG_A(kt + 2, 0, buf);
    if (kt < NT - 2) {
      asm volatile("s_waitcnt vmcnt(4)" ::: "memory");
    } else if (kt == NT - 2) {
      asm volatile("s_waitcnt vmcnt(0)" ::: "memory");
    }
    __builtin_amdgcn_s_barrier();
    asm volatile("" ::: "memory");
    MM(1, blo, 0);
    __builtin_amdgcn_s_barrier();
    asm volatile("" ::: "memory");
  }

  // epilogue: nf even = u, nf odd = v (same h-column group); SwiGLU in-register
#pragma unroll
  for (int mf = 0; mf < 8; mf++) {
#pragma unroll
    for (int p = 0; p < 2; p++) {
      f32x4 uu = acc[mf][2 * p], vv = acc[mf][2 * p + 1];
      int hcol = (nt * 8 + wn * 2 + p) * 16 + l15;
#pragma unroll
      for (int rr = 0; rr < 4; rr++) {
        int r_out = row0 + wr * 128 + mf * 16 + g4 * 4 + rr;
        float xx = uu[rr];
        float hh = (xx / (1.f + __expf(-xx))) * vv[rr];
        h_buf[(size_t)r_out * H_DIM + hcol] = f2bf(hh);
      }
    }
  }
}

// ---------------- pass B: y = h*W3 -> y_buf (bf16). 128x128, BK=32, 2-phase (proven) ----------------
__global__ __launch_bounds__(256, 3) void ffn2_kernel(
    const unsigned short* __restrict__ h_buf, const unsigned short* __restrict__ W3t,
    unsigned short* __restrict__ y_buf,
    const int* __restrict__ tile2e, const int* __restrict__ tile_row0) {
  const int NWG = MAXT * 8;   // 576, %8==0
  int orig = blockIdx.x;
  int wg = (orig & 7) * (NWG >> 3) + (orig >> 3);
  int f = wg >> 3, nt = wg & 7;
  int e = tile2e[f];
  if (e < 0) return;
  int row0 = tile_row0[f] + blockIdx.y * 128;

  __shared__ alignas(16) char ldsA[2][8192];
  __shared__ alignas(16) char ldsB[2][8192];

  int tid = threadIdx.x, w = tid >> 6, lane = tid & 63;
  int l15 = lane & 15, g4 = lane >> 4;
  int wr = w >> 1, wc = w & 1;

  int r = tid >> 2;
  int qs = (tid & 3) ^ ((r >> 1) & 3);
  const char* gA0 = (const char*)h_buf + (size_t)(row0 + r) * 4096 + qs * 16;
  const char* gA1 = (const char*)h_buf + (size_t)(row0 + r + 64) * 4096 + qs * 16;
  const char* W3e = (const char*)W3t + (size_t)e * 1024 * 4096;
  const char* gB0 = W3e + (size_t)(nt * 128 + r) * 4096 + qs * 16;
  const char* gB1 = W3e + (size_t)(nt * 128 + r + 64) * 4096 + qs * 16;

  auto STG = [&](int buf, int ks) {
    int ko = ks * 64;
    char* dA = &ldsA[buf][w * 1024];
    char* dB = &ldsB[buf][w * 1024];
    gload16(gA0 + ko, dA); gload16(gA1 + ko, dA + 4096);
    gload16(gB0 + ko, dB); gload16(gB1 + ko, dB + 4096);
  };

  int qr = g4 ^ ((l15 >> 1) & 3);
  int aoff[4], boff[4];
#pragma unroll
  for (int i = 0; i < 4; i++) {
    aoff[i] = (wr * 64 + i * 16 + l15) * 64 + qr * 16;
    boff[i] = (wc * 64 + i * 16 + l15) * 64 + qr * 16;
  }

  f32x4 acc[4][4];
#pragma unroll
  for (int i = 0; i < 4; i++)
#pragma unroll
    for (int j = 0; j < 4; j++) acc[i][j] = (f32x4){0.f, 0.f, 0.f, 0.f};

  const int NK = 64;
  STG(0, 0);
  __syncthreads();
#pragma unroll 1
  for (int ks = 0; ks < NK; ks++) {
    int cur = ks & 1;
    if (ks + 1 < NK) STG(cur ^ 1, ks + 1);
    short8 af[4], bf[4];
#pragma unroll
    for (int i = 0; i < 4; i++) {
      af[i] = *(const short8*)(&ldsA[cur][aoff[i]]);
      bf[i] = *(const short8*)(&ldsB[cur][boff[i]]);
    }
#pragma unroll
    for (int i = 0; i < 4; i++)
#pragma unroll
      for (int j = 0; j < 4; j++)
        acc[i][j] = __builtin_amdgcn_mfma_f32_16x16x32_bf16(af[i], bf[j], acc[i][j], 0, 0, 0);
    if (ks + 1 < NK) __syncthreads();
  }

#pragma unroll
  for (int mf = 0; mf < 4; mf++) {
#pragma unroll
    for (int nf = 0; nf < 4; nf++) {
      int col = nt * 128 + wc * 64 + nf * 16 + l15;
#pragma unroll
      for (int rr = 0; rr < 4; rr++) {
        int pos = row0 + wr * 64 + mf * 16 + g4 * 4 + rr;
        y_buf[(size_t)pos * D_DIM + col] = f2bf(acc[mf][nf][rr]);
      }
    }
  }
}

// ---------------- combine: out[t] = w0*y[pos0] + w1*y[pos1] ----------------
__global__ void combine_kernel(const unsigned short* __restrict__ y_buf,
                               const int2* __restrict__ tok_pos, const float* __restrict__ tok_w,
                               float* __restrict__ out) {
  int t = blockIdx.x * 2 + (threadIdx.x >> 7);
  int c = (threadIdx.x & 127) * 8;
  int2 p = tok_pos[t];
  float w0 = tok_w[2 * t], w1 = tok_w[2 * t + 1];
  u16x8 a = *(const u16x8*)(y_buf + (size_t)p.x * D_DIM + c);
  u16x8 b = *(const u16x8*)(y_buf + (size_t)p.y * D_DIM + c);
  float o[8];
#pragma unroll
  for (int k = 0; k < 8; k++) o[k] = w0 * bf2f(a[k]) + w1 * bf2f(b[k]);
  float4* op = (float4*)(out + (size_t)t * D_DIM + c);
  op[0] = make_float4(o[0], o[1], o[2], o[3]);
  op[1] = make_float4(o[4], o[5], o[6], o[7]);
}

// ---------------- launch ----------------
extern "C" void kernel_launch(void* const* d_in, const int* in_sizes, int n_in,
                              void* d_out, int out_size, void* d_ws, size_t ws_size,
                              hipStream_t stream) {
  const float* x  = (const float*)d_in[0];
  const float* Wg = (const float*)d_in[1];
  const float* W1 = (const float*)d_in[2];
  const float* W2 = (const float*)d_in[3];
  const float* W3 = (const float*)d_in[4];
  float* out = (float*)d_out;

  char* ws = (char*)d_ws;
  size_t off = 0;
  auto alloc = [&](size_t bytes) -> char* {
    char* p = ws + off; off += (bytes + 255) & ~(size_t)255; return p;
  };

  int*            cnt       = (int*)alloc(16 * 4);
  int*            poffs     = (int*)alloc(16 * 4);
  int*            run       = (int*)alloc(16 * 4);
  int*            tile2e    = (int*)alloc(80 * 4);
  int*            tile_row0 = (int*)alloc(80 * 4);
  int*            tok_e01   = (int*)alloc(T_TOKENS * 4);
  float*          tok_w     = (float*)alloc(T_TOKENS * 8);
  int2*           tok_pos   = (int2*)alloc(T_TOKENS * 8);
  int*            pair_tok  = (int*)alloc(MAXP * 4);
  unsigned short* xb        = (unsigned short*)alloc((size_t)T_TOKENS * D_DIM * 2);
  unsigned short* Bcat      = (unsigned short*)alloc((size_t)E_NUM * 4096 * 1024 * 2);
  unsigned short* W3t       = (unsigned short*)alloc((size_t)E_NUM * D_DIM * H_DIM * 2);
  unsigned short* h_buf     = (unsigned short*)alloc((size_t)MAXP * H_DIM * 2);
  unsigned short* y_buf     = Bcat;  // alias: Bcat dead after ffn1 (same stream)

  hipFuncSetAttribute((const void*)ffn1_kernel, hipFuncAttributeMaxDynamicSharedMemorySize, 131072);

  hipMemsetAsync(cnt, 0, 16 * 4, stream);
  hipMemsetAsync(run, 0, 16 * 4, stream);
  hipMemsetAsync(pair_tok, 0, MAXP * 4, stream);

  router_kernel<<<T_TOKENS / 4, 256, 0, stream>>>(x, Wg, cnt, tok_e01, tok_w);
  scan_kernel<<<1, 64, 0, stream>>>(cnt, poffs, tile2e, tile_row0);
  assign_kernel<<<T_TOKENS / 256, 256, 0, stream>>>(tok_e01, tok_w, poffs, run, pair_tok, tok_pos);
  cast_x_kernel<<<(T_TOKENS * D_DIM / 8) / 256, 256, 0, stream>>>(x, xb);
  dim3 tb(32, 8);
  cast_transpose_cat_kernel<<<dim3(H_DIM / 32, D_DIM / 32, E_NUM), tb, 0, stream>>>(W1, Bcat, 0);
  cast_transpose_cat_kernel<<<dim3(H_DIM / 32, D_DIM / 32, E_NUM), tb, 0, stream>>>(W2, Bcat, 1);
  cast_transpose_kernel<<<dim3(D_DIM / 32, H_DIM / 32, E_NUM), tb, 0, stream>>>(W3, W3t, H_DIM, D_DIM);

  ffn1_kernel<<<dim3(MAXT * 16), 512, 131072, stream>>>(xb, Bcat, h_buf, pair_tok, tile2e, tile_row0);
  ffn2_kernel<<<dim3(MAXT * 8, 2), 256, 0, stream>>>(h_buf, W3t, y_buf, tile2e, tile_row0);
  combine_kernel<<<T_TOKENS / 2, 256, 0, stream>>>(y_buf, tok_pos, tok_w, out);
}

// Round 6
// 431.680 us; speedup vs baseline: 2.0126x; 1.4536x over previous
//
#include <hip/hip_runtime.h>
#include <stdint.h>

#define T_TOKENS 8192
#define D_DIM 1024
#define H_DIM 2048
#define E_NUM 8
#define MAXP 18432         // pairs padded to 256/expert
#define MAXT 72            // max sum of per-expert ceil(cnt/256)
#define NCHUNK 32          // 8192/256 token chunks

typedef __attribute__((ext_vector_type(8))) short short8;
typedef __attribute__((ext_vector_type(4))) float f32x4;
typedef __attribute__((ext_vector_type(8))) unsigned short u16x8;

__device__ __forceinline__ unsigned short f2bf(float f) {
  union { float f; uint32_t u; } v; v.f = f;
  uint32_t r = (v.u + 0x7fffu + ((v.u >> 16) & 1u)) >> 16;
  return (unsigned short)r;
}

__device__ __forceinline__ float bf2f(unsigned short u) {
  union { uint32_t u; float f; } v; v.u = ((uint32_t)u) << 16;
  return v.f;
}

__device__ __forceinline__ void gload16(const void* g, void* l) {
  __builtin_amdgcn_global_load_lds((const __attribute__((address_space(1))) void*)g,
                                   (__attribute__((address_space(3))) void*)l, 16, 0, 0);
}

// ---------------- router: logits (f64 accum), top-2, softmax. NO atomics. ----------------
__global__ void router_kernel(const float* __restrict__ x, const float* __restrict__ Wg,
                              int* __restrict__ tok_e01, float* __restrict__ tok_w) {
  __shared__ float wgT[E_NUM * D_DIM];
  int tid = threadIdx.x;
  // conflict-free staging: consecutive threads -> consecutive d (distinct banks)
  for (int i = tid; i < D_DIM * E_NUM; i += 256) {
    int e = i >> 10, d = i & 1023;
    wgT[e * D_DIM + d] = Wg[d * E_NUM + e];
  }
  __syncthreads();
  int wid = tid >> 6, lane = tid & 63;
  int t = blockIdx.x * 4 + wid;
  const float* xr = x + (size_t)t * D_DIM;
  double acc[E_NUM];
#pragma unroll
  for (int e = 0; e < E_NUM; e++) acc[e] = 0.0;
  for (int i = 0; i < D_DIM / 64; i++) {
    double xv = (double)xr[i * 64 + lane];
#pragma unroll
    for (int e = 0; e < E_NUM; e++) acc[e] += xv * (double)wgT[e * D_DIM + i * 64 + lane];
  }
#pragma unroll
  for (int e = 0; e < E_NUM; e++) {
    double v = acc[e];
#pragma unroll
    for (int off = 32; off >= 1; off >>= 1) v += __shfl_xor(v, off);
    acc[e] = v;
  }
  if (lane == 0) {
    int e0 = 0; double l0 = acc[0];
#pragma unroll
    for (int e = 1; e < E_NUM; e++) if (acc[e] > l0) { l0 = acc[e]; e0 = e; }
    int e1 = -1; double l1 = -1e300;
#pragma unroll
    for (int e = 0; e < E_NUM; e++) if (e != e0 && acc[e] > l1) { l1 = acc[e]; e1 = e; }
    float z1 = expf((float)(l1 - l0));
    float w0 = 1.f / (1.f + z1);
    float w1 = z1 * w0;
    tok_e01[t] = e0 | (e1 << 8);
    tok_w[2 * t] = w0; tok_w[2 * t + 1] = w1;
  }
}

// ---------------- hist: ballot-based chunk histograms + offsets + tile table (1 block) ----------------
__global__ void hist_kernel(const int* __restrict__ tok_e01, int* __restrict__ poffs,
                            int* __restrict__ tile2e, int* __restrict__ tile_row0,
                            int* __restrict__ chunk_base) {
  __shared__ int chist[NCHUNK][E_NUM];
  int tid = threadIdx.x, wv = tid >> 6, lane = tid & 63;  // 16 waves
  // wave wv covers chunks 2wv, 2wv+1 (4 iters of 64 tokens each)
#pragma unroll
  for (int half = 0; half < 2; half++) {
    int myc = 0;  // count for expert == lane (lane < 8)
#pragma unroll
    for (int it = 0; it < 4; it++) {
      int t = wv * 512 + half * 256 + it * 64 + lane;
      int p = tok_e01[t];
      int e0 = p & 255, e1 = (p >> 8) & 255;
#pragma unroll
      for (int e = 0; e < E_NUM; e++) {
        unsigned long long b0 = __ballot(e0 == e);
        unsigned long long b1 = __ballot(e1 == e);
        if (lane == e) myc += __popcll(b0) + __popcll(b1);
      }
    }
    if (lane < E_NUM) chist[wv * 2 + half][lane] = myc;
  }
  __syncthreads();
  if (tid == 0) {
    int tot[E_NUM];
    for (int e = 0; e < E_NUM; e++) {
      int s = 0;
      for (int c = 0; c < NCHUNK; c++) s += chist[c][e];
      tot[e] = s;
    }
    int po = 0, tf = 0;
    for (int e = 0; e < E_NUM; e++) {
      poffs[e] = po;
      int nt = (tot[e] + 255) >> 8;
      for (int i = 0; i < nt; i++) { tile2e[tf] = e; tile_row0[tf] = po + i * 256; tf++; }
      po += nt << 8;
    }
    for (; tf < MAXT; tf++) { tile2e[tf] = -1; tile_row0[tf] = 0; }
    for (int e = 0; e < E_NUM; e++) {
      int s = poffs[e];
      for (int c = 0; c < NCHUNK; c++) { chunk_base[c * E_NUM + e] = s; s += chist[c][e]; }
    }
  }
}

// ---------------- assign: deterministic ballot-rank, zero contended atomics ----------------
__global__ void assign_kernel(const int* __restrict__ tok_e01, const int* __restrict__ chunk_base,
                              int* __restrict__ pair_tok, int2* __restrict__ tok_pos) {
  __shared__ int wcnt[4][E_NUM];
  __shared__ int woff[4][E_NUM];
  int tid = threadIdx.x, wv = tid >> 6, lane = tid & 63;
  int t = blockIdx.x * 256 + tid;
  int p = tok_e01[t];
  int e0 = p & 255, e1 = (p >> 8) & 255;
  unsigned long long lt = (lane == 63) ? ~0ull >> 1 : (1ull << lane) - 1;
  int rank0 = 0, rank1 = 0, myc = 0;
#pragma unroll
  for (int e = 0; e < E_NUM; e++) {
    unsigned long long b0 = __ballot(e0 == e);
    unsigned long long b1 = __ballot(e1 == e);
    int n0 = __popcll(b0);
    if (e0 == e) rank0 = __popcll(b0 & lt);
    if (e1 == e) rank1 = n0 + __popcll(b1 & lt);
    if (lane == e) myc = n0 + __popcll(b1);
  }
  if (lane < E_NUM) wcnt[wv][lane] = myc;
  __syncthreads();
  if (tid < E_NUM) {
    int s = 0;
    for (int w = 0; w < 4; w++) { woff[w][tid] = s; s += wcnt[w][tid]; }
  }
  __syncthreads();
  int cb = blockIdx.x * E_NUM;
  int pos0 = chunk_base[cb + e0] + woff[wv][e0] + rank0;
  int pos1 = chunk_base[cb + e1] + woff[wv][e1] + rank1;
  pair_tok[pos0] = t;
  pair_tok[pos1] = t;
  tok_pos[t] = make_int2(pos0, pos1);
}

// ---------------- casts ----------------
__global__ void cast_x_kernel(const float* __restrict__ x, unsigned short* __restrict__ xb) {
  int i = blockIdx.x * 256 + threadIdx.x;
  const float4* xp = (const float4*)x;
  float4 a = xp[2 * i], b = xp[2 * i + 1];
  u16x8 r;
  r[0] = f2bf(a.x); r[1] = f2bf(a.y); r[2] = f2bf(a.z); r[3] = f2bf(a.w);
  r[4] = f2bf(b.x); r[5] = f2bf(b.y); r[6] = f2bf(b.z); r[7] = f2bf(b.w);
  *(u16x8*)(xb + (size_t)i * 8) = r;
}

// W3: [E][H][D] f32 -> [E][D][H] bf16 (N-major, K contiguous)
__global__ void cast_transpose_kernel(const float* __restrict__ in, unsigned short* __restrict__ out,
                                      int R, int C) {
  __shared__ float tile[32][33];
  int e = blockIdx.z;
  const float* src = in + (size_t)e * R * C;
  unsigned short* dst = out + (size_t)e * R * C;
  int c0 = blockIdx.x * 32, r0 = blockIdx.y * 32;
  int tx = threadIdx.x, ty = threadIdx.y;
#pragma unroll
  for (int i = 0; i < 4; i++)
    tile[ty + i * 8][tx] = src[(size_t)(r0 + ty + i * 8) * C + c0 + tx];
  __syncthreads();
#pragma unroll
  for (int i = 0; i < 4; i++)
    dst[(size_t)(c0 + ty + i * 8) * R + r0 + tx] = f2bf(tile[tx][ty + i * 8]);
}

// W1/W2: [E][D][H] f32 -> Bcat [E][4096][1024] bf16, 16-col interleave (u / v per 32-row group)
__global__ void cast_transpose_cat_kernel(const float* __restrict__ in, unsigned short* __restrict__ Bcat,
                                          int isV) {
  __shared__ float tile[32][33];
  int e = blockIdx.z;
  const float* src = in + (size_t)e * D_DIM * H_DIM;
  unsigned short* dst = Bcat + (size_t)e * 4096 * 1024;
  int c0 = blockIdx.x * 32, r0 = blockIdx.y * 32;
  int tx = threadIdx.x, ty = threadIdx.y;
#pragma unroll
  for (int i = 0; i < 4; i++)
    tile[ty + i * 8][tx] = src[(size_t)(r0 + ty + i * 8) * H_DIM + c0 + tx];
  __syncthreads();
#pragma unroll
  for (int i = 0; i < 4; i++) {
    int n = c0 + ty + i * 8;
    int nr = ((n >> 4) << 5) + (n & 15) + isV * 16;
    dst[(size_t)nr * 1024 + r0 + tx] = f2bf(tile[tx][ty + i * 8]);
  }
}

// ---------------- pass A: 8-phase-class 256x256 deep pipeline ----------------
__global__ __launch_bounds__(512, 2) void ffn1_kernel(
    const unsigned short* __restrict__ xb, const unsigned short* __restrict__ Bcat,
    unsigned short* __restrict__ h_buf,
    const int* __restrict__ pair_tok, const int* __restrict__ tile2e,
    const int* __restrict__ tile_row0) {
  extern __shared__ char lds[];
  char* ldsB = lds + 65536;
  const int NWG = MAXT * 16;  // 1152, %8==0
  int orig = blockIdx.x;
  int wg = (orig & 7) * (NWG >> 3) + (orig >> 3);
  int f = wg >> 4, nt = wg & 15;
  int e = tile2e[f];
  if (e < 0) return;
  int row0 = tile_row0[f];

  int tid = threadIdx.x;
  int w = tid >> 6, lane = tid & 63;
  int l15 = lane & 15, g4 = lane >> 4;
  int wr = w >> 2, wn = w & 3;

  int s0 = w * 64 + lane;
  int r0_ = s0 >> 3, c0_ = s0 & 7;
  int kc = c0_ ^ (r0_ & 7);
  const char* gA[2][2];
  const char* gB[2][2];
  const char* Bce = (const char*)Bcat + (size_t)e * 4096 * 2048;
#pragma unroll
  for (int h = 0; h < 2; h++) {
    int tokA0 = pair_tok[row0 + h * 128 + r0_];
    int tokA1 = pair_tok[row0 + h * 128 + r0_ + 64];
    gA[h][0] = (const char*)xb + (size_t)tokA0 * 2048 + kc * 16;
    gA[h][1] = (const char*)xb + (size_t)tokA1 * 2048 + kc * 16;
    gB[h][0] = Bce + (size_t)(nt * 256 + h * 128 + r0_) * 2048 + kc * 16;
    gB[h][1] = Bce + (size_t)(nt * 256 + h * 128 + r0_ + 64) * 2048 + kc * 16;
  }

  auto STG_A = [&](int kt, int h, int buf) {
    char* d = lds + buf * 32768 + h * 16384 + w * 1024;
    gload16(gA[h][0] + kt * 128, d);
    gload16(gA[h][1] + kt * 128, d + 8192);
  };
  auto STG_B = [&](int kt, int h, int buf) {
    char* d = ldsB + buf * 32768 + h * 16384 + w * 1024;
    gload16(gB[h][0] + kt * 128, d);
    gload16(gB[h][1] + kt * 128, d + 8192);
  };

  int sw = l15 & 7;
  int cbase = (sw >> 2) * 64 + ((g4 ^ (sw & 3)) * 16);
  int aRow = wr * 16384 + l15 * 128;
  int bRow = 65536 + wn * 8192 + l15 * 128;

  f32x4 acc[8][4];
#pragma unroll
  for (int i = 0; i < 8; i++)
#pragma unroll
    for (int j = 0; j < 4; j++) acc[i][j] = (f32x4){0.f, 0.f, 0.f, 0.f};

  short8 a[4][2], blo[2][2], bhi[2][2];
  auto RD_A = [&](int mq, int buf) {
    const char* base = lds + buf * 32768 + aRow + mq * 8192;
#pragma unroll
    for (int m2 = 0; m2 < 4; m2++)
#pragma unroll
      for (int ks = 0; ks < 2; ks++)
        a[m2][ks] = *(const short8*)(base + m2 * 2048 + (cbase ^ (ks << 6)));
  };
  auto RD_B = [&](short8 (&b)[2][2], int nq, int buf) {
    const char* base = lds + buf * 32768 + bRow + nq * 4096;
#pragma unroll
    for (int n2 = 0; n2 < 2; n2++)
#pragma unroll
      for (int ks = 0; ks < 2; ks++)
        b[n2][ks] = *(const short8*)(base + n2 * 2048 + (cbase ^ (ks << 6)));
  };
  auto MM = [&](int mq, short8 (&b)[2][2], int nq) {
    __builtin_amdgcn_s_setprio(1);
#pragma unroll
    for (int m2 = 0; m2 < 4; m2++)
#pragma unroll
      for (int n2 = 0; n2 < 2; n2++)
#pragma unroll
        for (int ks = 0; ks < 2; ks++)
          acc[mq * 4 + m2][nq * 2 + n2] = __builtin_amdgcn_mfma_f32_16x16x32_bf16(
              a[m2][ks], b[n2][ks], acc[mq * 4 + m2][nq * 2 + n2], 0, 0, 0);
    __builtin_amdgcn_s_setprio(0);
  };

  STG_A(0, 0, 0); STG_A(0, 1, 0); STG_B(0, 0, 0); STG_B(0, 1, 0);
  STG_B(1, 0, 1); STG_A(1, 0, 1);
  asm volatile("s_waitcnt vmcnt(4)" ::: "memory");
  __builtin_amdgcn_s_barrier();
  asm volatile("" ::: "memory");

  const int NT = 16;
#pragma unroll 1
  for (int kt = 0; kt < NT; kt++) {
    int buf = kt & 1;
    RD_A(0, buf); RD_B(blo, 0, buf);
    if (kt + 1 < NT) STG_A(kt + 1, 1, buf ^ 1);
    __builtin_amdgcn_s_barrier();
    asm volatile("" ::: "memory");
    MM(0, blo, 0);
    __builtin_amdgcn_s_barrier();
    asm volatile("" ::: "memory");
    RD_B(bhi, 1, buf);
    if (kt + 1 < NT) STG_B(kt + 1, 1, buf ^ 1);
    __builtin_amdgcn_s_barrier();
    asm volatile("" ::: "memory");
    MM(0, bhi, 1);
    __builtin_amdgcn_s_barrier();
    asm volatile("" ::: "memory");
    RD_A(1, buf);
    if (kt + 2 < NT) STG_B(kt + 2, 0, buf);
    __builtin_amdgcn_s_barrier();
    asm volatile("" ::: "memory");
    MM(1, bhi, 1);
    __builtin_amdgcn_s_barrier();
    asm volatile("" ::: "memory");
    if (kt + 2 < NT) STG_A(kt + 2, 0, buf);
    if (kt < NT - 2) {
      asm volatile("s_waitcnt vmcnt(4)" ::: "memory");
    } else if (kt == NT - 2) {
      asm volatile("s_waitcnt vmcnt(0)" ::: "memory");
    }
    __builtin_amdgcn_s_barrier();
    asm volatile("" ::: "memory");
    MM(1, blo, 0);
    __builtin_amdgcn_s_barrier();
    asm volatile("" ::: "memory");
  }

#pragma unroll
  for (int mf = 0; mf < 8; mf++) {
#pragma unroll
    for (int p = 0; p < 2; p++) {
      f32x4 uu = acc[mf][2 * p], vv = acc[mf][2 * p + 1];
      int hcol = (nt * 8 + wn * 2 + p) * 16 + l15;
#pragma unroll
      for (int rr = 0; rr < 4; rr++) {
        int r_out = row0 + wr * 128 + mf * 16 + g4 * 4 + rr;
        float xx = uu[rr];
        float hh = (xx / (1.f + __expf(-xx))) * vv[rr];
        h_buf[(size_t)r_out * H_DIM + hcol] = f2bf(hh);
      }
    }
  }
}

// ---------------- pass B: y = h*W3 -> y_buf (bf16). 128x128, BK=32, 2-phase ----------------
__global__ __launch_bounds__(256, 3) void ffn2_kernel(
    const unsigned short* __restrict__ h_buf, const unsigned short* __restrict__ W3t,
    unsigned short* __restrict__ y_buf,
    const int* __restrict__ tile2e, const int* __restrict__ tile_row0) {
  const int NWG = MAXT * 8;   // 576, %8==0
  int orig = blockIdx.x;
  int wg = (orig & 7) * (NWG >> 3) + (orig >> 3);
  int f = wg >> 3, nt = wg & 7;
  int e = tile2e[f];
  if (e < 0) return;
  int row0 = tile_row0[f] + blockIdx.y * 128;

  __shared__ alignas(16) char ldsA[2][8192];
  __shared__ alignas(16) char ldsB[2][8192];

  int tid = threadIdx.x, w = tid >> 6, lane = tid & 63;
  int l15 = lane & 15, g4 = lane >> 4;
  int wr = w >> 1, wc = w & 1;

  int r = tid >> 2;
  int qs = (tid & 3) ^ ((r >> 1) & 3);
  const char* gA0 = (const char*)h_buf + (size_t)(row0 + r) * 4096 + qs * 16;
  const char* gA1 = (const char*)h_buf + (size_t)(row0 + r + 64) * 4096 + qs * 16;
  const char* W3e = (const char*)W3t + (size_t)e * 1024 * 4096;
  const char* gB0 = W3e + (size_t)(nt * 128 + r) * 4096 + qs * 16;
  const char* gB1 = W3e + (size_t)(nt * 128 + r + 64) * 4096 + qs * 16;

  auto STG = [&](int buf, int ks) {
    int ko = ks * 64;
    char* dA = &ldsA[buf][w * 1024];
    char* dB = &ldsB[buf][w * 1024];
    gload16(gA0 + ko, dA); gload16(gA1 + ko, dA + 4096);
    gload16(gB0 + ko, dB); gload16(gB1 + ko, dB + 4096);
  };

  int qr = g4 ^ ((l15 >> 1) & 3);
  int aoff[4], boff[4];
#pragma unroll
  for (int i = 0; i < 4; i++) {
    aoff[i] = (wr * 64 + i * 16 + l15) * 64 + qr * 16;
    boff[i] = (wc * 64 + i * 16 + l15) * 64 + qr * 16;
  }

  f32x4 acc[4][4];
#pragma unroll
  for (int i = 0; i < 4; i++)
#pragma unroll
    for (int j = 0; j < 4; j++) acc[i][j] = (f32x4){0.f, 0.f, 0.f, 0.f};

  const int NK = 64;
  STG(0, 0);
  __syncthreads();
#pragma unroll 1
  for (int ks = 0; ks < NK; ks++) {
    int cur = ks & 1;
    if (ks + 1 < NK) STG(cur ^ 1, ks + 1);
    short8 af[4], bf[4];
#pragma unroll
    for (int i = 0; i < 4; i++) {
      af[i] = *(const short8*)(&ldsA[cur][aoff[i]]);
      bf[i] = *(const short8*)(&ldsB[cur][boff[i]]);
    }
#pragma unroll
    for (int i = 0; i < 4; i++)
#pragma unroll
      for (int j = 0; j < 4; j++)
        acc[i][j] = __builtin_amdgcn_mfma_f32_16x16x32_bf16(af[i], bf[j], acc[i][j], 0, 0, 0);
    if (ks + 1 < NK) __syncthreads();
  }

#pragma unroll
  for (int mf = 0; mf < 4; mf++) {
#pragma unroll
    for (int nf = 0; nf < 4; nf++) {
      int col = nt * 128 + wc * 64 + nf * 16 + l15;
#pragma unroll
      for (int rr = 0; rr < 4; rr++) {
        int pos = row0 + wr * 64 + mf * 16 + g4 * 4 + rr;
        y_buf[(size_t)pos * D_DIM + col] = f2bf(acc[mf][nf][rr]);
      }
    }
  }
}

// ---------------- combine: out[t] = w0*y[pos0] + w1*y[pos1] ----------------
__global__ void combine_kernel(const unsigned short* __restrict__ y_buf,
                               const int2* __restrict__ tok_pos, const float* __restrict__ tok_w,
                               float* __restrict__ out) {
  int t = blockIdx.x * 2 + (threadIdx.x >> 7);
  int c = (threadIdx.x & 127) * 8;
  int2 p = tok_pos[t];
  float w0 = tok_w[2 * t], w1 = tok_w[2 * t + 1];
  u16x8 a = *(const u16x8*)(y_buf + (size_t)p.x * D_DIM + c);
  u16x8 b = *(const u16x8*)(y_buf + (size_t)p.y * D_DIM + c);
  float o[8];
#pragma unroll
  for (int k = 0; k < 8; k++) o[k] = w0 * bf2f(a[k]) + w1 * bf2f(b[k]);
  float4* op = (float4*)(out + (size_t)t * D_DIM + c);
  op[0] = make_float4(o[0], o[1], o[2], o[3]);
  op[1] = make_float4(o[4], o[5], o[6], o[7]);
}

// ---------------- launch ----------------
extern "C" void kernel_launch(void* const* d_in, const int* in_sizes, int n_in,
                              void* d_out, int out_size, void* d_ws, size_t ws_size,
                              hipStream_t stream) {
  const float* x  = (const float*)d_in[0];
  const float* Wg = (const float*)d_in[1];
  const float* W1 = (const float*)d_in[2];
  const float* W2 = (const float*)d_in[3];
  const float* W3 = (const float*)d_in[4];
  float* out = (float*)d_out;

  char* ws = (char*)d_ws;
  size_t off = 0;
  auto alloc = [&](size_t bytes) -> char* {
    char* p = ws + off; off += (bytes + 255) & ~(size_t)255; return p;
  };

  int*            poffs      = (int*)alloc(16 * 4);
  int*            tile2e     = (int*)alloc(80 * 4);
  int*            tile_row0  = (int*)alloc(80 * 4);
  int*            chunk_base = (int*)alloc(NCHUNK * E_NUM * 4);
  int*            tok_e01    = (int*)alloc(T_TOKENS * 4);
  float*          tok_w      = (float*)alloc(T_TOKENS * 8);
  int2*           tok_pos    = (int2*)alloc(T_TOKENS * 8);
  int*            pair_tok   = (int*)alloc(MAXP * 4);
  unsigned short* xb         = (unsigned short*)alloc((size_t)T_TOKENS * D_DIM * 2);
  unsigned short* Bcat       = (unsigned short*)alloc((size_t)E_NUM * 4096 * 1024 * 2);
  unsigned short* W3t        = (unsigned short*)alloc((size_t)E_NUM * D_DIM * H_DIM * 2);
  unsigned short* h_buf      = (unsigned short*)alloc((size_t)MAXP * H_DIM * 2);
  unsigned short* y_buf      = Bcat;  // alias: Bcat dead after ffn1 (same stream)

  hipFuncSetAttribute((const void*)ffn1_kernel, hipFuncAttributeMaxDynamicSharedMemorySize, 131072);

  hipMemsetAsync(pair_tok, 0, MAXP * 4, stream);

  router_kernel<<<T_TOKENS / 4, 256, 0, stream>>>(x, Wg, tok_e01, tok_w);
  hist_kernel<<<1, 1024, 0, stream>>>(tok_e01, poffs, tile2e, tile_row0, chunk_base);
  assign_kernel<<<NCHUNK, 256, 0, stream>>>(tok_e01, chunk_base, pair_tok, tok_pos);
  cast_x_kernel<<<(T_TOKENS * D_DIM / 8) / 256, 256, 0, stream>>>(x, xb);
  dim3 tb(32, 8);
  cast_transpose_cat_kernel<<<dim3(H_DIM / 32, D_DIM / 32, E_NUM), tb, 0, stream>>>(W1, Bcat, 0);
  cast_transpose_cat_kernel<<<dim3(H_DIM / 32, D_DIM / 32, E_NUM), tb, 0, stream>>>(W2, Bcat, 1);
  cast_transpose_kernel<<<dim3(D_DIM / 32, H_DIM / 32, E_NUM), tb, 0, stream>>>(W3, W3t, H_DIM, D_DIM);

  ffn1_kernel<<<dim3(MAXT * 16), 512, 131072, stream>>>(xb, Bcat, h_buf, pair_tok, tile2e, tile_row0);
  ffn2_kernel<<<dim3(MAXT * 8, 2), 256, 0, stream>>>(h_buf, W3t, y_buf, tile2e, tile_row0);
  combine_kernel<<<T_TOKENS / 2, 256, 0, stream>>>(y_buf, tok_pos, tok_w, out);
}

// Round 8
// 429.554 us; speedup vs baseline: 2.0226x; 1.0050x over previous
//
#include <hip/hip_runtime.h>
#include <stdint.h>

#define T_TOKENS 8192
#define D_DIM 1024
#define H_DIM 2048
#define E_NUM 8
#define MAXP 18432         // pairs padded to 256/expert
#define MAXT 72            // max sum of per-expert ceil(cnt/256)
#define NCHUNK 32          // 8192/256 token chunks

typedef __attribute__((ext_vector_type(8))) short short8;
typedef __attribute__((ext_vector_type(4))) float f32x4;
typedef __attribute__((ext_vector_type(8))) unsigned short u16x8;

__device__ __forceinline__ unsigned short f2bf(float f) {
  union { float f; uint32_t u; } v; v.f = f;
  uint32_t r = (v.u + 0x7fffu + ((v.u >> 16) & 1u)) >> 16;
  return (unsigned short)r;
}

__device__ __forceinline__ float bf2f(unsigned short u) {
  union { uint32_t u; float f; } v; v.u = ((uint32_t)u) << 16;
  return v.f;
}

__device__ __forceinline__ void gload16(const void* g, void* l) {
  __builtin_amdgcn_global_load_lds((const __attribute__((address_space(1))) void*)g,
                                   (__attribute__((address_space(3))) void*)l, 16, 0, 0);
}

// ---------------- router: logits (f64 accum), top-2, softmax. NO atomics. ----------------
__global__ void router_kernel(const float* __restrict__ x, const float* __restrict__ Wg,
                              int* __restrict__ tok_e01, float* __restrict__ tok_w) {
  __shared__ float wgT[E_NUM * D_DIM];
  int tid = threadIdx.x;
  for (int i = tid; i < D_DIM * E_NUM; i += 256) {
    int e = i >> 10, d = i & 1023;
    wgT[e * D_DIM + d] = Wg[d * E_NUM + e];
  }
  __syncthreads();
  int wid = tid >> 6, lane = tid & 63;
  int t = blockIdx.x * 4 + wid;
  const float* xr = x + (size_t)t * D_DIM;
  double acc[E_NUM];
#pragma unroll
  for (int e = 0; e < E_NUM; e++) acc[e] = 0.0;
  for (int i = 0; i < D_DIM / 64; i++) {
    double xv = (double)xr[i * 64 + lane];
#pragma unroll
    for (int e = 0; e < E_NUM; e++) acc[e] += xv * (double)wgT[e * D_DIM + i * 64 + lane];
  }
#pragma unroll
  for (int e = 0; e < E_NUM; e++) {
    double v = acc[e];
#pragma unroll
    for (int off = 32; off >= 1; off >>= 1) v += __shfl_xor(v, off);
    acc[e] = v;
  }
  if (lane == 0) {
    int e0 = 0; double l0 = acc[0];
#pragma unroll
    for (int e = 1; e < E_NUM; e++) if (acc[e] > l0) { l0 = acc[e]; e0 = e; }
    int e1 = -1; double l1 = -1e300;
#pragma unroll
    for (int e = 0; e < E_NUM; e++) if (e != e0 && acc[e] > l1) { l1 = acc[e]; e1 = e; }
    float z1 = expf((float)(l1 - l0));
    float w0 = 1.f / (1.f + z1);
    float w1 = z1 * w0;
    tok_e01[t] = e0 | (e1 << 8);
    tok_w[2 * t] = w0; tok_w[2 * t + 1] = w1;
  }
}

// ---------------- hist: ballot-based chunk histograms + offsets + tile table (1 block) ----------------
__global__ void hist_kernel(const int* __restrict__ tok_e01, int* __restrict__ poffs,
                            int* __restrict__ tile2e, int* __restrict__ tile_row0,
                            int* __restrict__ chunk_base) {
  __shared__ int chist[NCHUNK][E_NUM];
  int tid = threadIdx.x, wv = tid >> 6, lane = tid & 63;  // 16 waves
#pragma unroll
  for (int half = 0; half < 2; half++) {
    int myc = 0;
#pragma unroll
    for (int it = 0; it < 4; it++) {
      int t = wv * 512 + half * 256 + it * 64 + lane;
      int p = tok_e01[t];
      int e0 = p & 255, e1 = (p >> 8) & 255;
#pragma unroll
      for (int e = 0; e < E_NUM; e++) {
        unsigned long long b0 = __ballot(e0 == e);
        unsigned long long b1 = __ballot(e1 == e);
        if (lane == e) myc += __popcll(b0) + __popcll(b1);
      }
    }
    if (lane < E_NUM) chist[wv * 2 + half][lane] = myc;
  }
  __syncthreads();
  if (tid == 0) {
    int tot[E_NUM];
    for (int e = 0; e < E_NUM; e++) {
      int s = 0;
      for (int c = 0; c < NCHUNK; c++) s += chist[c][e];
      tot[e] = s;
    }
    int po = 0, tf = 0;
    for (int e = 0; e < E_NUM; e++) {
      poffs[e] = po;
      int nt = (tot[e] + 255) >> 8;
      for (int i = 0; i < nt; i++) { tile2e[tf] = e; tile_row0[tf] = po + i * 256; tf++; }
      po += nt << 8;
    }
    for (; tf < MAXT; tf++) { tile2e[tf] = -1; tile_row0[tf] = 0; }
    for (int e = 0; e < E_NUM; e++) {
      int s = poffs[e];
      for (int c = 0; c < NCHUNK; c++) { chunk_base[c * E_NUM + e] = s; s += chist[c][e]; }
    }
  }
}

// ---------------- assign: deterministic ballot-rank, zero contended atomics ----------------
__global__ void assign_kernel(const int* __restrict__ tok_e01, const int* __restrict__ chunk_base,
                              int* __restrict__ pair_tok, int2* __restrict__ tok_pos) {
  __shared__ int wcnt[4][E_NUM];
  __shared__ int woff[4][E_NUM];
  int tid = threadIdx.x, wv = tid >> 6, lane = tid & 63;
  int t = blockIdx.x * 256 + tid;
  int p = tok_e01[t];
  int e0 = p & 255, e1 = (p >> 8) & 255;
  unsigned long long lt = (lane == 63) ? ~0ull >> 1 : (1ull << lane) - 1;
  int rank0 = 0, rank1 = 0, myc = 0;
#pragma unroll
  for (int e = 0; e < E_NUM; e++) {
    unsigned long long b0 = __ballot(e0 == e);
    unsigned long long b1 = __ballot(e1 == e);
    int n0 = __popcll(b0);
    if (e0 == e) rank0 = __popcll(b0 & lt);
    if (e1 == e) rank1 = n0 + __popcll(b1 & lt);
    if (lane == e) myc = n0 + __popcll(b1);
  }
  if (lane < E_NUM) wcnt[wv][lane] = myc;
  __syncthreads();
  if (tid < E_NUM) {
    int s = 0;
    for (int w = 0; w < 4; w++) { woff[w][tid] = s; s += wcnt[w][tid]; }
  }
  __syncthreads();
  int cb = blockIdx.x * E_NUM;
  int pos0 = chunk_base[cb + e0] + woff[wv][e0] + rank0;
  int pos1 = chunk_base[cb + e1] + woff[wv][e1] + rank1;
  pair_tok[pos0] = t;
  pair_tok[pos1] = t;
  tok_pos[t] = make_int2(pos0, pos1);
}

// ---------------- casts ----------------
__global__ void cast_x_kernel(const float* __restrict__ x, unsigned short* __restrict__ xb) {
  int i = blockIdx.x * 256 + threadIdx.x;
  const float4* xp = (const float4*)x;
  float4 a = xp[2 * i], b = xp[2 * i + 1];
  u16x8 r;
  r[0] = f2bf(a.x); r[1] = f2bf(a.y); r[2] = f2bf(a.z); r[3] = f2bf(a.w);
  r[4] = f2bf(b.x); r[5] = f2bf(b.y); r[6] = f2bf(b.z); r[7] = f2bf(b.w);
  *(u16x8*)(xb + (size_t)i * 8) = r;
}

// [E][R][C] f32 -> transposed bf16, 64x64 tiles, float4 loads, coalesced u16x8 stores.
// dst per-expert stride is e_stride ELEMENTS (Bcat = 4096*1024, W3t = 2048*1024).
// cat=1 applies the Bcat 16-col interleave row remap (voff=0 for W1/u, 1 for W2/v).
__global__ void cast_transpose64_kernel(const float* __restrict__ in, unsigned short* __restrict__ out,
                                        int R, int C, size_t e_stride, int cat, int voff) {
  __shared__ float tile[64][68];
  int e = blockIdx.z;
  const float* src = in + (size_t)e * R * C;
  unsigned short* dst = out + (size_t)e * e_stride;
  int c0 = blockIdx.x * 64, r0 = blockIdx.y * 64;
  int tl = threadIdx.x;
  int lr = tl >> 4, lc = (tl & 15) * 4;
#pragma unroll
  for (int p = 0; p < 4; p++) {
    float4 v = *(const float4*)(src + (size_t)(r0 + p * 16 + lr) * C + c0 + lc);
    *(float4*)&tile[p * 16 + lr][lc] = v;
  }
  __syncthreads();
  int cc = tl >> 2, rchunk = (tl & 3) * 16;
  int n = c0 + cc;
  int outrow = cat ? (((n >> 4) << 5) + (n & 15) + voff * 16) : n;
  u16x8 o0, o1;
#pragma unroll
  for (int k = 0; k < 8; k++) o0[k] = f2bf(tile[rchunk + k][cc]);
#pragma unroll
  for (int k = 0; k < 8; k++) o1[k] = f2bf(tile[rchunk + 8 + k][cc]);
  unsigned short* dp = dst + (size_t)outrow * R + r0 + rchunk;
  *(u16x8*)dp = o0;
  *(u16x8*)(dp + 8) = o1;
}

// ---------------- pass A: 8-phase-class 256x256 deep pipeline (fused SwiGLU via Bcat) ----------------
__global__ __launch_bounds__(512, 2) void ffn1_kernel(
    const unsigned short* __restrict__ xb, const unsigned short* __restrict__ Bcat,
    unsigned short* __restrict__ h_buf,
    const int* __restrict__ pair_tok, const int* __restrict__ tile2e,
    const int* __restrict__ tile_row0) {
  extern __shared__ char lds[];
  char* ldsB = lds + 65536;
  const int NWG = MAXT * 16;  // 1152, %8==0
  int orig = blockIdx.x;
  int wg = (orig & 7) * (NWG >> 3) + (orig >> 3);
  int f = wg >> 4, nt = wg & 15;
  int e = tile2e[f];
  if (e < 0) return;
  int row0 = tile_row0[f];

  int tid = threadIdx.x;
  int w = tid >> 6, lane = tid & 63;
  int l15 = lane & 15, g4 = lane >> 4;
  int wr = w >> 2, wn = w & 3;

  int s0 = w * 64 + lane;
  int r0_ = s0 >> 3, c0_ = s0 & 7;
  int kc = c0_ ^ (r0_ & 7);
  const char* gA[2][2];
  const char* gB[2][2];
  const char* Bce = (const char*)Bcat + (size_t)e * 4096 * 2048;
#pragma unroll
  for (int h = 0; h < 2; h++) {
    int tokA0 = pair_tok[row0 + h * 128 + r0_];
    int tokA1 = pair_tok[row0 + h * 128 + r0_ + 64];
    gA[h][0] = (const char*)xb + (size_t)tokA0 * 2048 + kc * 16;
    gA[h][1] = (const char*)xb + (size_t)tokA1 * 2048 + kc * 16;
    gB[h][0] = Bce + (size_t)(nt * 256 + h * 128 + r0_) * 2048 + kc * 16;
    gB[h][1] = Bce + (size_t)(nt * 256 + h * 128 + r0_ + 64) * 2048 + kc * 16;
  }

  auto STG_A = [&](int kt, int h, int buf) {
    char* d = lds + buf * 32768 + h * 16384 + w * 1024;
    gload16(gA[h][0] + kt * 128, d);
    gload16(gA[h][1] + kt * 128, d + 8192);
  };
  auto STG_B = [&](int kt, int h, int buf) {
    char* d = ldsB + buf * 32768 + h * 16384 + w * 1024;
    gload16(gB[h][0] + kt * 128, d);
    gload16(gB[h][1] + kt * 128, d + 8192);
  };

  int sw = l15 & 7;
  int cbase = (sw >> 2) * 64 + ((g4 ^ (sw & 3)) * 16);
  int aRow = wr * 16384 + l15 * 128;
  int bRow = 65536 + wn * 8192 + l15 * 128;

  f32x4 acc[8][4];
#pragma unroll
  for (int i = 0; i < 8; i++)
#pragma unroll
    for (int j = 0; j < 4; j++) acc[i][j] = (f32x4){0.f, 0.f, 0.f, 0.f};

  short8 a[4][2], blo[2][2], bhi[2][2];
  auto RD_A = [&](int mq, int buf) {
    const char* base = lds + buf * 32768 + aRow + mq * 8192;
#pragma unroll
    for (int m2 = 0; m2 < 4; m2++)
#pragma unroll
      for (int ks = 0; ks < 2; ks++)
        a[m2][ks] = *(const short8*)(base + m2 * 2048 + (cbase ^ (ks << 6)));
  };
  auto RD_B = [&](short8 (&b)[2][2], int nq, int buf) {
    const char* base = lds + buf * 32768 + bRow + nq * 4096;
#pragma unroll
    for (int n2 = 0; n2 < 2; n2++)
#pragma unroll
      for (int ks = 0; ks < 2; ks++)
        b[n2][ks] = *(const short8*)(base + n2 * 2048 + (cbase ^ (ks << 6)));
  };
  auto MM = [&](int mq, short8 (&b)[2][2], int nq) {
    __builtin_amdgcn_s_setprio(1);
#pragma unroll
    for (int m2 = 0; m2 < 4; m2++)
#pragma unroll
      for (int n2 = 0; n2 < 2; n2++)
#pragma unroll
        for (int ks = 0; ks < 2; ks++)
          acc[mq * 4 + m2][nq * 2 + n2] = __builtin_amdgcn_mfma_f32_16x16x32_bf16(
              a[m2][ks], b[n2][ks], acc[mq * 4 + m2][nq * 2 + n2], 0, 0, 0);
    __builtin_amdgcn_s_setprio(0);
  };

  STG_A(0, 0, 0); STG_A(0, 1, 0); STG_B(0, 0, 0); STG_B(0, 1, 0);
  STG_B(1, 0, 1); STG_A(1, 0, 1);
  asm volatile("s_waitcnt vmcnt(4)" ::: "memory");
  __builtin_amdgcn_s_barrier();
  asm volatile("" ::: "memory");

  const int NT = 16;
#pragma unroll 1
  for (int kt = 0; kt < NT; kt++) {
    int buf = kt & 1;
    RD_A(0, buf); RD_B(blo, 0, buf);
    if (kt + 1 < NT) STG_A(kt + 1, 1, buf ^ 1);
    __builtin_amdgcn_s_barrier();
    asm volatile("" ::: "memory");
    MM(0, blo, 0);
    __builtin_amdgcn_s_barrier();
    asm volatile("" ::: "memory");
    RD_B(bhi, 1, buf);
    if (kt + 1 < NT) STG_B(kt + 1, 1, buf ^ 1);
    __builtin_amdgcn_s_barrier();
    asm volatile("" ::: "memory");
    MM(0, bhi, 1);
    __builtin_amdgcn_s_barrier();
    asm volatile("" ::: "memory");
    RD_A(1, buf);
    if (kt + 2 < NT) STG_B(kt + 2, 0, buf);
    __builtin_amdgcn_s_barrier();
    asm volatile("" ::: "memory");
    MM(1, bhi, 1);
    __builtin_amdgcn_s_barrier();
    asm volatile("" ::: "memory");
    if (kt + 2 < NT) STG_A(kt + 2, 0, buf);
    if (kt < NT - 2) {
      asm volatile("s_waitcnt vmcnt(4)" ::: "memory");
    } else if (kt == NT - 2) {
      asm volatile("s_waitcnt vmcnt(0)" ::: "memory");
    }
    __builtin_amdgcn_s_barrier();
    asm volatile("" ::: "memory");
    MM(1, blo, 0);
    __builtin_amdgcn_s_barrier();
    asm volatile("" ::: "memory");
  }

#pragma unroll
  for (int mf = 0; mf < 8; mf++) {
#pragma unroll
    for (int p = 0; p < 2; p++) {
      f32x4 uu = acc[mf][2 * p], vv = acc[mf][2 * p + 1];
      int hcol = (nt * 8 + wn * 2 + p) * 16 + l15;
#pragma unroll
      for (int rr = 0; rr < 4; rr++) {
        int r_out = row0 + wr * 128 + mf * 16 + g4 * 4 + rr;
        float xx = uu[rr];
        float hh = (xx / (1.f + __expf(-xx))) * vv[rr];
        h_buf[(size_t)r_out * H_DIM + hcol] = f2bf(hh);
      }
    }
  }
}

// ---------------- pass B: y = h*W3 -> y_buf. Same 8-phase 256x256 engine, NT=32 ----------------
__global__ __launch_bounds__(512, 2) void ffn2_kernel(
    const unsigned short* __restrict__ h_buf, const unsigned short* __restrict__ W3t,
    unsigned short* __restrict__ y_buf,
    const int* __restrict__ tile2e, const int* __restrict__ tile_row0) {
  extern __shared__ char lds[];
  char* ldsB = lds + 65536;
  const int NWG = MAXT * 4;  // 288, %8==0
  int orig = blockIdx.x;
  int wg = (orig & 7) * (NWG >> 3) + (orig >> 3);
  int f = wg >> 2, nt = wg & 3;
  int e = tile2e[f];
  if (e < 0) return;
  int row0 = tile_row0[f];

  int tid = threadIdx.x;
  int w = tid >> 6, lane = tid & 63;
  int l15 = lane & 15, g4 = lane >> 4;
  int wr = w >> 2, wn = w & 3;

  int s0 = w * 64 + lane;
  int r0_ = s0 >> 3, c0_ = s0 & 7;
  int kc = c0_ ^ (r0_ & 7);
  const char* gA[2][2];
  const char* gB[2][2];
  const char* W3e = (const char*)W3t + (size_t)e * 1024 * 4096;
#pragma unroll
  for (int h = 0; h < 2; h++) {
    gA[h][0] = (const char*)h_buf + (size_t)(row0 + h * 128 + r0_) * 4096 + kc * 16;
    gA[h][1] = (const char*)h_buf + (size_t)(row0 + h * 128 + r0_ + 64) * 4096 + kc * 16;
    gB[h][0] = W3e + (size_t)(nt * 256 + h * 128 + r0_) * 4096 + kc * 16;
    gB[h][1] = W3e + (size_t)(nt * 256 + h * 128 + r0_ + 64) * 4096 + kc * 16;
  }

  auto STG_A = [&](int kt, int h, int buf) {
    char* d = lds + buf * 32768 + h * 16384 + w * 1024;
    gload16(gA[h][0] + kt * 128, d);
    gload16(gA[h][1] + kt * 128, d + 8192);
  };
  auto STG_B = [&](int kt, int h, int buf) {
    char* d = ldsB + buf * 32768 + h * 16384 + w * 1024;
    gload16(gB[h][0] + kt * 128, d);
    gload16(gB[h][1] + kt * 128, d + 8192);
  };

  int sw = l15 & 7;
  int cbase = (sw >> 2) * 64 + ((g4 ^ (sw & 3)) * 16);
  int aRow = wr * 16384 + l15 * 128;
  int bRow = 65536 + wn * 8192 + l15 * 128;

  f32x4 acc[8][4];
#pragma unroll
  for (int i = 0; i < 8; i++)
#pragma unroll
    for (int j = 0; j < 4; j++) acc[i][j] = (f32x4){0.f, 0.f, 0.f, 0.f};

  short8 a[4][2], blo[2][2], bhi[2][2];
  auto RD_A = [&](int mq, int buf) {
    const char* base = lds + buf * 32768 + aRow + mq * 8192;
#pragma unroll
    for (int m2 = 0; m2 < 4; m2++)
#pragma unroll
      for (int ks = 0; ks < 2; ks++)
        a[m2][ks] = *(const short8*)(base + m2 * 2048 + (cbase ^ (ks << 6)));
  };
  auto RD_B = [&](short8 (&b)[2][2], int nq, int buf) {
    const char* base = lds + buf * 32768 + bRow + nq * 4096;
#pragma unroll
    for (int n2 = 0; n2 < 2; n2++)
#pragma unroll
      for (int ks = 0; ks < 2; ks++)
        b[n2][ks] = *(const short8*)(base + n2 * 2048 + (cbase ^ (ks << 6)));
  };
  auto MM = [&](int mq, short8 (&b)[2][2], int nq) {
    __builtin_amdgcn_s_setprio(1);
#pragma unroll
    for (int m2 = 0; m2 < 4; m2++)
#pragma unroll
      for (int n2 = 0; n2 < 2; n2++)
#pragma unroll
        for (int ks = 0; ks < 2; ks++)
          acc[mq * 4 + m2][nq * 2 + n2] = __builtin_amdgcn_mfma_f32_16x16x32_bf16(
              a[m2][ks], b[n2][ks], acc[mq * 4 + m2][nq * 2 + n2], 0, 0, 0);
    __builtin_amdgcn_s_setprio(0);
  };

  STG_A(0, 0, 0); STG_A(0, 1, 0); STG_B(0, 0, 0); STG_B(0, 1, 0);
  STG_B(1, 0, 1); STG_A(1, 0, 1);
  asm volatile("s_waitcnt vmcnt(4)" ::: "memory");
  __builtin_amdgcn_s_barrier();
  asm volatile("" ::: "memory");

  const int NT = 32;
#pragma unroll 1
  for (int kt = 0; kt < NT; kt++) {
    int buf = kt & 1;
    RD_A(0, buf); RD_B(blo, 0, buf);
    if (kt + 1 < NT) STG_A(kt + 1, 1, buf ^ 1);
    __builtin_amdgcn_s_barrier();
    asm volatile("" ::: "memory");
    MM(0, blo, 0);
    __builtin_amdgcn_s_barrier();
    asm volatile("" ::: "memory");
    RD_B(bhi, 1, buf);
    if (kt + 1 < NT) STG_B(kt + 1, 1, buf ^ 1);
    __builtin_amdgcn_s_barrier();
    asm volatile("" ::: "memory");
    MM(0, bhi, 1);
    __builtin_amdgcn_s_barrier();
    asm volatile("" ::: "memory");
    RD_A(1, buf);
    if (kt + 2 < NT) STG_B(kt + 2, 0, buf);
    __builtin_amdgcn_s_barrier();
    asm volatile("" ::: "memory");
    MM(1, bhi, 1);
    __builtin_amdgcn_s_barrier();
    asm volatile("" ::: "memory");
    if (kt + 2 < NT) STG_A(kt + 2, 0, buf);
    if (kt < NT - 2) {
      asm volatile("s_waitcnt vmcnt(4)" ::: "memory");
    } else if (kt == NT - 2) {
      asm volatile("s_waitcnt vmcnt(0)" ::: "memory");
    }
    __builtin_amdgcn_s_barrier();
    asm volatile("" ::: "memory");
    MM(1, blo, 0);
    __builtin_amdgcn_s_barrier();
    asm volatile("" ::: "memory");
  }

#pragma unroll
  for (int mf = 0; mf < 8; mf++) {
#pragma unroll
    for (int nf = 0; nf < 4; nf++) {
      int col = nt * 256 + wn * 64 + nf * 16 + l15;
#pragma unroll
      for (int rr = 0; rr < 4; rr++) {
        int pos = row0 + wr * 128 + mf * 16 + g4 * 4 + rr;
        y_buf[(size_t)pos * D_DIM + col] = f2bf(acc[mf][nf][rr]);
      }
    }
  }
}

// ---------------- combine: out[t] = w0*y[pos0] + w1*y[pos1] ----------------
__global__ void combine_kernel(const unsigned short* __restrict__ y_buf,
                               const int2* __restrict__ tok_pos, const float* __restrict__ tok_w,
                               float* __restrict__ out) {
  int t = blockIdx.x * 2 + (threadIdx.x >> 7);
  int c = (threadIdx.x & 127) * 8;
  int2 p = tok_pos[t];
  float w0 = tok_w[2 * t], w1 = tok_w[2 * t + 1];
  u16x8 a = *(const u16x8*)(y_buf + (size_t)p.x * D_DIM + c);
  u16x8 b = *(const u16x8*)(y_buf + (size_t)p.y * D_DIM + c);
  float o[8];
#pragma unroll
  for (int k = 0; k < 8; k++) o[k] = w0 * bf2f(a[k]) + w1 * bf2f(b[k]);
  float4* op = (float4*)(out + (size_t)t * D_DIM + c);
  op[0] = make_float4(o[0], o[1], o[2], o[3]);
  op[1] = make_float4(o[4], o[5], o[6], o[7]);
}

// ---------------- launch ----------------
extern "C" void kernel_launch(void* const* d_in, const int* in_sizes, int n_in,
                              void* d_out, int out_size, void* d_ws, size_t ws_size,
                              hipStream_t stream) {
  const float* x  = (const float*)d_in[0];
  const float* Wg = (const float*)d_in[1];
  const float* W1 = (const float*)d_in[2];
  const float* W2 = (const float*)d_in[3];
  const float* W3 = (const float*)d_in[4];
  float* out = (float*)d_out;

  char* ws = (char*)d_ws;
  size_t off = 0;
  auto alloc = [&](size_t bytes) -> char* {
    char* p = ws + off; off += (bytes + 255) & ~(size_t)255; return p;
  };

  int*            poffs      = (int*)alloc(16 * 4);
  int*            tile2e     = (int*)alloc(80 * 4);
  int*            tile_row0  = (int*)alloc(80 * 4);
  int*            chunk_base = (int*)alloc(NCHUNK * E_NUM * 4);
  int*            tok_e01    = (int*)alloc(T_TOKENS * 4);
  float*          tok_w      = (float*)alloc(T_TOKENS * 8);
  int2*           tok_pos    = (int2*)alloc(T_TOKENS * 8);
  int*            pair_tok   = (int*)alloc(MAXP * 4);
  unsigned short* xb         = (unsigned short*)alloc((size_t)T_TOKENS * D_DIM * 2);
  unsigned short* Bcat       = (unsigned short*)alloc((size_t)E_NUM * 4096 * 1024 * 2);
  unsigned short* W3t        = (unsigned short*)alloc((size_t)E_NUM * D_DIM * H_DIM * 2);
  unsigned short* h_buf      = (unsigned short*)alloc((size_t)MAXP * H_DIM * 2);
  unsigned short* y_buf      = Bcat;  // alias: Bcat dead after ffn1 (same stream)

  hipFuncSetAttribute((const void*)ffn1_kernel, hipFuncAttributeMaxDynamicSharedMemorySize, 131072);
  hipFuncSetAttribute((const void*)ffn2_kernel, hipFuncAttributeMaxDynamicSharedMemorySize, 131072);

  hipMemsetAsync(pair_tok, 0, MAXP * 4, stream);

  router_kernel<<<T_TOKENS / 4, 256, 0, stream>>>(x, Wg, tok_e01, tok_w);
  hist_kernel<<<1, 1024, 0, stream>>>(tok_e01, poffs, tile2e, tile_row0, chunk_base);
  assign_kernel<<<NCHUNK, 256, 0, stream>>>(tok_e01, chunk_base, pair_tok, tok_pos);
  cast_x_kernel<<<(T_TOKENS * D_DIM / 8) / 256, 256, 0, stream>>>(x, xb);
  // W1/W2 -> Bcat (interleaved, per-expert stride 4096*1024), W3 -> W3t (stride 2048*1024).
  cast_transpose64_kernel<<<dim3(H_DIM / 64, D_DIM / 64, E_NUM), 256, 0, stream>>>(
      W1, Bcat, D_DIM, H_DIM, (size_t)4096 * 1024, 1, 0);
  cast_transpose64_kernel<<<dim3(H_DIM / 64, D_DIM / 64, E_NUM), 256, 0, stream>>>(
      W2, Bcat, D_DIM, H_DIM, (size_t)4096 * 1024, 1, 1);
  cast_transpose64_kernel<<<dim3(D_DIM / 64, H_DIM / 64, E_NUM), 256, 0, stream>>>(
      W3, W3t, H_DIM, D_DIM, (size_t)2048 * 1024, 0, 0);

  ffn1_kernel<<<dim3(MAXT * 16), 512, 131072, stream>>>(xb, Bcat, h_buf, pair_tok, tile2e, tile_row0);
  ffn2_kernel<<<dim3(MAXT * 4), 512, 131072, stream>>>(h_buf, W3t, y_buf, tile2e, tile_row0);
  combine_kernel<<<T_TOKENS / 2, 256, 0, stream>>>(y_buf, tok_pos, tok_w, out);
}

// Round 11
// 420.828 us; speedup vs baseline: 2.0645x; 1.0207x over previous
//
#include <hip/hip_runtime.h>
#include <stdint.h>

#define T_TOKENS 8192
#define D_DIM 1024
#define H_DIM 2048
#define E_NUM 8
#define MAXP 18432         // pairs padded to 256/expert
#define MAXT 72            // max sum of per-expert ceil(cnt/256)
#define NCHUNK 32          // 8192/256 token chunks

typedef __attribute__((ext_vector_type(8))) short short8;
typedef __attribute__((ext_vector_type(4))) float f32x4;
typedef __attribute__((ext_vector_type(8))) unsigned short u16x8;

__device__ __forceinline__ unsigned short f2bf(float f) {
  union { float f; uint32_t u; } v; v.f = f;
  uint32_t r = (v.u + 0x7fffu + ((v.u >> 16) & 1u)) >> 16;
  return (unsigned short)r;
}

__device__ __forceinline__ float bf2f(unsigned short u) {
  union { uint32_t u; float f; } v; v.u = ((uint32_t)u) << 16;
  return v.f;
}

__device__ __forceinline__ void gload16(const void* g, void* l) {
  __builtin_amdgcn_global_load_lds((const __attribute__((address_space(1))) void*)g,
                                   (__attribute__((address_space(3))) void*)l, 16, 0, 0);
}

// ---------------- router: logits (f64 accum), top-2, softmax. NO atomics. ----------------
__global__ void router_kernel(const float* __restrict__ x, const float* __restrict__ Wg,
                              int* __restrict__ tok_e01, float* __restrict__ tok_w) {
  __shared__ float wgT[E_NUM * D_DIM];
  int tid = threadIdx.x;
  for (int i = tid; i < D_DIM * E_NUM; i += 256) {
    int e = i >> 10, d = i & 1023;
    wgT[e * D_DIM + d] = Wg[d * E_NUM + e];
  }
  __syncthreads();
  int wid = tid >> 6, lane = tid & 63;
  int t = blockIdx.x * 4 + wid;
  const float* xr = x + (size_t)t * D_DIM;
  double acc[E_NUM];
#pragma unroll
  for (int e = 0; e < E_NUM; e++) acc[e] = 0.0;
  for (int i = 0; i < D_DIM / 64; i++) {
    double xv = (double)xr[i * 64 + lane];
#pragma unroll
    for (int e = 0; e < E_NUM; e++) acc[e] += xv * (double)wgT[e * D_DIM + i * 64 + lane];
  }
#pragma unroll
  for (int e = 0; e < E_NUM; e++) {
    double v = acc[e];
#pragma unroll
    for (int off = 32; off >= 1; off >>= 1) v += __shfl_xor(v, off);
    acc[e] = v;
  }
  if (lane == 0) {
    int e0 = 0; double l0 = acc[0];
#pragma unroll
    for (int e = 1; e < E_NUM; e++) if (acc[e] > l0) { l0 = acc[e]; e0 = e; }
    int e1 = -1; double l1 = -1e300;
#pragma unroll
    for (int e = 0; e < E_NUM; e++) if (e != e0 && acc[e] > l1) { l1 = acc[e]; e1 = e; }
    float z1 = expf((float)(l1 - l0));
    float w0 = 1.f / (1.f + z1);
    float w1 = z1 * w0;
    tok_e01[t] = e0 | (e1 << 8);
    tok_w[2 * t] = w0; tok_w[2 * t + 1] = w1;
  }
}

// ---------------- hist: ballot-based chunk histograms + offsets + tile table (1 block) ----------------
__global__ void hist_kernel(const int* __restrict__ tok_e01, int* __restrict__ poffs,
                            int* __restrict__ tile2e, int* __restrict__ tile_row0,
                            int* __restrict__ chunk_base) {
  __shared__ int chist[NCHUNK][E_NUM];
  int tid = threadIdx.x, wv = tid >> 6, lane = tid & 63;  // 16 waves
#pragma unroll
  for (int half = 0; half < 2; half++) {
    int myc = 0;
#pragma unroll
    for (int it = 0; it < 4; it++) {
      int t = wv * 512 + half * 256 + it * 64 + lane;
      int p = tok_e01[t];
      int e0 = p & 255, e1 = (p >> 8) & 255;
#pragma unroll
      for (int e = 0; e < E_NUM; e++) {
        unsigned long long b0 = __ballot(e0 == e);
        unsigned long long b1 = __ballot(e1 == e);
        if (lane == e) myc += __popcll(b0) + __popcll(b1);
      }
    }
    if (lane < E_NUM) chist[wv * 2 + half][lane] = myc;
  }
  __syncthreads();
  if (tid == 0) {
    int tot[E_NUM];
    for (int e = 0; e < E_NUM; e++) {
      int s = 0;
      for (int c = 0; c < NCHUNK; c++) s += chist[c][e];
      tot[e] = s;
    }
    int po = 0, tf = 0;
    for (int e = 0; e < E_NUM; e++) {
      poffs[e] = po;
      int nt = (tot[e] + 255) >> 8;
      for (int i = 0; i < nt; i++) { tile2e[tf] = e; tile_row0[tf] = po + i * 256; tf++; }
      po += nt << 8;
    }
    for (; tf < MAXT; tf++) { tile2e[tf] = -1; tile_row0[tf] = 0; }
    for (int e = 0; e < E_NUM; e++) {
      int s = poffs[e];
      for (int c = 0; c < NCHUNK; c++) { chunk_base[c * E_NUM + e] = s; s += chist[c][e]; }
    }
  }
}

// ---------------- assign: deterministic ballot-rank, zero contended atomics ----------------
__global__ void assign_kernel(const int* __restrict__ tok_e01, const int* __restrict__ chunk_base,
                              int* __restrict__ pair_tok, int2* __restrict__ tok_pos) {
  __shared__ int wcnt[4][E_NUM];
  __shared__ int woff[4][E_NUM];
  int tid = threadIdx.x, wv = tid >> 6, lane = tid & 63;
  int t = blockIdx.x * 256 + tid;
  int p = tok_e01[t];
  int e0 = p & 255, e1 = (p >> 8) & 255;
  unsigned long long lt = (lane == 63) ? ~0ull >> 1 : (1ull << lane) - 1;
  int rank0 = 0, rank1 = 0, myc = 0;
#pragma unroll
  for (int e = 0; e < E_NUM; e++) {
    unsigned long long b0 = __ballot(e0 == e);
    unsigned long long b1 = __ballot(e1 == e);
    int n0 = __popcll(b0);
    if (e0 == e) rank0 = __popcll(b0 & lt);
    if (e1 == e) rank1 = n0 + __popcll(b1 & lt);
    if (lane == e) myc = n0 + __popcll(b1);
  }
  if (lane < E_NUM) wcnt[wv][lane] = myc;
  __syncthreads();
  if (tid < E_NUM) {
    int s = 0;
    for (int w = 0; w < 4; w++) { woff[w][tid] = s; s += wcnt[w][tid]; }
  }
  __syncthreads();
  int cb = blockIdx.x * E_NUM;
  int pos0 = chunk_base[cb + e0] + woff[wv][e0] + rank0;
  int pos1 = chunk_base[cb + e1] + woff[wv][e1] + rank1;
  pair_tok[pos0] = t;
  pair_tok[pos1] = t;
  tok_pos[t] = make_int2(pos0, pos1);
}

// ---------------- casts ----------------
__global__ void cast_x_kernel(const float* __restrict__ x, unsigned short* __restrict__ xb) {
  int i = blockIdx.x * 256 + threadIdx.x;
  const float4* xp = (const float4*)x;
  float4 a = xp[2 * i], b = xp[2 * i + 1];
  u16x8 r;
  r[0] = f2bf(a.x); r[1] = f2bf(a.y); r[2] = f2bf(a.z); r[3] = f2bf(a.w);
  r[4] = f2bf(b.x); r[5] = f2bf(b.y); r[6] = f2bf(b.z); r[7] = f2bf(b.w);
  *(u16x8*)(xb + (size_t)i * 8) = r;
}

// [E][R][C] f32 -> transposed bf16, 64x64 tiles, float4 loads, coalesced u16x8 stores.
// dst per-expert stride = e_stride ELEMENTS. cat=1: Bcat 16-col interleave (voff 0=u, 1=v).
__global__ void cast_transpose64_kernel(const float* __restrict__ in, unsigned short* __restrict__ out,
                                        int R, int C, size_t e_stride, int cat, int voff) {
  __shared__ float tile[64][68];
  int e = blockIdx.z;
  const float* src = in + (size_t)e * R * C;
  unsigned short* dst = out + (size_t)e * e_stride;
  int c0 = blockIdx.x * 64, r0 = blockIdx.y * 64;
  int tl = threadIdx.x;
  int lr = tl >> 4, lc = (tl & 15) * 4;
#pragma unroll
  for (int p = 0; p < 4; p++) {
    float4 v = *(const float4*)(src + (size_t)(r0 + p * 16 + lr) * C + c0 + lc);
    *(float4*)&tile[p * 16 + lr][lc] = v;
  }
  __syncthreads();
  int cc = tl >> 2, rchunk = (tl & 3) * 16;
  int n = c0 + cc;
  int outrow = cat ? (((n >> 4) << 5) + (n & 15) + voff * 16) : n;
  u16x8 o0, o1;
#pragma unroll
  for (int k = 0; k < 8; k++) o0[k] = f2bf(tile[rchunk + k][cc]);
#pragma unroll
  for (int k = 0; k < 8; k++) o1[k] = f2bf(tile[rchunk + 8 + k][cc]);
  unsigned short* dp = dst + (size_t)outrow * R + r0 + rchunk;
  *(u16x8*)dp = o0;
  *(u16x8*)(dp + 8) = o1;
}

// ---------------- pass A: 8-phase-class 256x256 deep pipeline (fused SwiGLU via Bcat) ----------------
// VERIFIED 4-phase schedule (round 8). Do not merge phases.
__global__ __launch_bounds__(512, 2) void ffn1_kernel(
    const unsigned short* __restrict__ xb, const unsigned short* __restrict__ Bcat,
    unsigned short* __restrict__ h_buf,
    const int* __restrict__ pair_tok, const int* __restrict__ tile2e,
    const int* __restrict__ tile_row0) {
  extern __shared__ char lds[];
  char* ldsB = lds + 65536;
  const int NWG = MAXT * 16;  // 1152, %8==0
  int orig = blockIdx.x;
  int wg = (orig & 7) * (NWG >> 3) + (orig >> 3);
  int f = wg >> 4, nt = wg & 15;
  int e = tile2e[f];
  if (e < 0) return;
  int row0 = tile_row0[f];

  int tid = threadIdx.x;
  int w = tid >> 6, lane = tid & 63;
  int l15 = lane & 15, g4 = lane >> 4;
  int wr = w >> 2, wn = w & 3;

  int s0 = w * 64 + lane;
  int r0_ = s0 >> 3, c0_ = s0 & 7;
  int kc = c0_ ^ (r0_ & 7);
  const char* gA[2][2];
  const char* gB[2][2];
  const char* Bce = (const char*)Bcat + (size_t)e * 4096 * 2048;
#pragma unroll
  for (int h = 0; h < 2; h++) {
    int tokA0 = pair_tok[row0 + h * 128 + r0_];
    int tokA1 = pair_tok[row0 + h * 128 + r0_ + 64];
    gA[h][0] = (const char*)xb + (size_t)tokA0 * 2048 + kc * 16;
    gA[h][1] = (const char*)xb + (size_t)tokA1 * 2048 + kc * 16;
    gB[h][0] = Bce + (size_t)(nt * 256 + h * 128 + r0_) * 2048 + kc * 16;
    gB[h][1] = Bce + (size_t)(nt * 256 + h * 128 + r0_ + 64) * 2048 + kc * 16;
  }

  auto STG_A = [&](int kt, int h, int buf) {
    char* d = lds + buf * 32768 + h * 16384 + w * 1024;
    gload16(gA[h][0] + kt * 128, d);
    gload16(gA[h][1] + kt * 128, d + 8192);
  };
  auto STG_B = [&](int kt, int h, int buf) {
    char* d = ldsB + buf * 32768 + h * 16384 + w * 1024;
    gload16(gB[h][0] + kt * 128, d);
    gload16(gB[h][1] + kt * 128, d + 8192);
  };

  int sw = l15 & 7;
  int cbase = (sw >> 2) * 64 + ((g4 ^ (sw & 3)) * 16);
  int aRow = wr * 16384 + l15 * 128;
  int bRow = 65536 + wn * 8192 + l15 * 128;

  f32x4 acc[8][4];
#pragma unroll
  for (int i = 0; i < 8; i++)
#pragma unroll
    for (int j = 0; j < 4; j++) acc[i][j] = (f32x4){0.f, 0.f, 0.f, 0.f};

  short8 a[4][2], blo[2][2], bhi[2][2];
  auto RD_A = [&](int mq, int buf) {
    const char* base = lds + buf * 32768 + aRow + mq * 8192;
#pragma unroll
    for (int m2 = 0; m2 < 4; m2++)
#pragma unroll
      for (int ks = 0; ks < 2; ks++)
        a[m2][ks] = *(const short8*)(base + m2 * 2048 + (cbase ^ (ks << 6)));
  };
  auto RD_B = [&](short8 (&b)[2][2], int nq, int buf) {
    const char* base = lds + buf * 32768 + bRow + nq * 4096;
#pragma unroll
    for (int n2 = 0; n2 < 2; n2++)
#pragma unroll
      for (int ks = 0; ks < 2; ks++)
        b[n2][ks] = *(const short8*)(base + n2 * 2048 + (cbase ^ (ks << 6)));
  };
  auto MM = [&](int mq, short8 (&b)[2][2], int nq) {
    __builtin_amdgcn_s_setprio(1);
#pragma unroll
    for (int m2 = 0; m2 < 4; m2++)
#pragma unroll
      for (int n2 = 0; n2 < 2; n2++)
#pragma unroll
        for (int ks = 0; ks < 2; ks++)
          acc[mq * 4 + m2][nq * 2 + n2] = __builtin_amdgcn_mfma_f32_16x16x32_bf16(
              a[m2][ks], b[n2][ks], acc[mq * 4 + m2][nq * 2 + n2], 0, 0, 0);
    __builtin_amdgcn_s_setprio(0);
  };

  STG_A(0, 0, 0); STG_A(0, 1, 0); STG_B(0, 0, 0); STG_B(0, 1, 0);
  STG_B(1, 0, 1); STG_A(1, 0, 1);
  asm volatile("s_waitcnt vmcnt(4)" ::: "memory");
  __builtin_amdgcn_s_barrier();
  asm volatile("" ::: "memory");

  const int NT = 16;
#pragma unroll 1
  for (int kt = 0; kt < NT; kt++) {
    int buf = kt & 1;
    RD_A(0, buf); RD_B(blo, 0, buf);
    if (kt + 1 < NT) STG_A(kt + 1, 1, buf ^ 1);
    __builtin_amdgcn_s_barrier();
    asm volatile("" ::: "memory");
    MM(0, blo, 0);
    __builtin_amdgcn_s_barrier();
    asm volatile("" ::: "memory");
    RD_B(bhi, 1, buf);
    if (kt + 1 < NT) STG_B(kt + 1, 1, buf ^ 1);
    __builtin_amdgcn_s_barrier();
    asm volatile("" ::: "memory");
    MM(0, bhi, 1);
    __builtin_amdgcn_s_barrier();
    asm volatile("" ::: "memory");
    RD_A(1, buf);
    if (kt + 2 < NT) STG_B(kt + 2, 0, buf);
    __builtin_amdgcn_s_barrier();
    asm volatile("" ::: "memory");
    MM(1, bhi, 1);
    __builtin_amdgcn_s_barrier();
    asm volatile("" ::: "memory");
    if (kt + 2 < NT) STG_A(kt + 2, 0, buf);
    if (kt < NT - 2) {
      asm volatile("s_waitcnt vmcnt(4)" ::: "memory");
    } else if (kt == NT - 2) {
      asm volatile("s_waitcnt vmcnt(0)" ::: "memory");
    }
    __builtin_amdgcn_s_barrier();
    asm volatile("" ::: "memory");
    MM(1, blo, 0);
    __builtin_amdgcn_s_barrier();
    asm volatile("" ::: "memory");
  }

#pragma unroll
  for (int mf = 0; mf < 8; mf++) {
#pragma unroll
    for (int p = 0; p < 2; p++) {
      f32x4 uu = acc[mf][2 * p], vv = acc[mf][2 * p + 1];
      int hcol = (nt * 8 + wn * 2 + p) * 16 + l15;
#pragma unroll
      for (int rr = 0; rr < 4; rr++) {
        int r_out = row0 + wr * 128 + mf * 16 + g4 * 4 + rr;
        float xx = uu[rr];
        float hh = (xx / (1.f + __expf(-xx))) * vv[rr];
        h_buf[(size_t)r_out * H_DIM + hcol] = f2bf(hh);
      }
    }
  }
}

// ---------------- pass B: y = h*W3, K-split x2 -> bf16 partials. Verified 4-phase, NT=16 ----------------
__global__ __launch_bounds__(512, 2) void ffn2_kernel(
    const unsigned short* __restrict__ h_buf, const unsigned short* __restrict__ W3t,
    unsigned short* __restrict__ y_buf,   // [2][MAXP][1024] partials (75.5 MB!)
    const int* __restrict__ tile2e, const int* __restrict__ tile_row0) {
  extern __shared__ char lds[];
  char* ldsB = lds + 65536;
  const int NWG = MAXT * 8;  // 576, %8==0 : f x 4 nt x 2 kseg
  int orig = blockIdx.x;
  int wg = (orig & 7) * (NWG >> 3) + (orig >> 3);
  int f = wg >> 3;
  int r8 = wg & 7;
  int nt = r8 >> 1, kseg = r8 & 1;
  int e = tile2e[f];
  if (e < 0) return;
  int row0 = tile_row0[f];

  int tid = threadIdx.x;
  int w = tid >> 6, lane = tid & 63;
  int l15 = lane & 15, g4 = lane >> 4;
  int wr = w >> 2, wn = w & 3;

  int s0 = w * 64 + lane;
  int r0_ = s0 >> 3, c0_ = s0 & 7;
  int kc = c0_ ^ (r0_ & 7);
  const char* gA[2][2];
  const char* gB[2][2];
  const char* W3e = (const char*)W3t + (size_t)e * 1024 * 4096;
  int kbase = kseg * 2048;  // byte offset: 1024 k-elems * 2B
#pragma unroll
  for (int h = 0; h < 2; h++) {
    gA[h][0] = (const char*)h_buf + (size_t)(row0 + h * 128 + r0_) * 4096 + kbase + kc * 16;
    gA[h][1] = (const char*)h_buf + (size_t)(row0 + h * 128 + r0_ + 64) * 4096 + kbase + kc * 16;
    gB[h][0] = W3e + (size_t)(nt * 256 + h * 128 + r0_) * 4096 + kbase + kc * 16;
    gB[h][1] = W3e + (size_t)(nt * 256 + h * 128 + r0_ + 64) * 4096 + kbase + kc * 16;
  }

  auto STG_A = [&](int kt, int h, int buf) {
    char* d = lds + buf * 32768 + h * 16384 + w * 1024;
    gload16(gA[h][0] + kt * 128, d);
    gload16(gA[h][1] + kt * 128, d + 8192);
  };
  auto STG_B = [&](int kt, int h, int buf) {
    char* d = ldsB + buf * 32768 + h * 16384 + w * 1024;
    gload16(gB[h][0] + kt * 128, d);
    gload16(gB[h][1] + kt * 128, d + 8192);
  };

  int sw = l15 & 7;
  int cbase = (sw >> 2) * 64 + ((g4 ^ (sw & 3)) * 16);
  int aRow = wr * 16384 + l15 * 128;
  int bRow = 65536 + wn * 8192 + l15 * 128;

  f32x4 acc[8][4];
#pragma unroll
  for (int i = 0; i < 8; i++)
#pragma unroll
    for (int j = 0; j < 4; j++) acc[i][j] = (f32x4){0.f, 0.f, 0.f, 0.f};

  short8 a[4][2], blo[2][2], bhi[2][2];
  auto RD_A = [&](int mq, int buf) {
    const char* base = lds + buf * 32768 + aRow + mq * 8192;
#pragma unroll
    for (int m2 = 0; m2 < 4; m2++)
#pragma unroll
      for (int ks = 0; ks < 2; ks++)
        a[m2][ks] = *(const short8*)(base + m2 * 2048 + (cbase ^ (ks << 6)));
  };
  auto RD_B = [&](short8 (&b)[2][2], int nq, int buf) {
    const char* base = lds + buf * 32768 + bRow + nq * 4096;
#pragma unroll
    for (int n2 = 0; n2 < 2; n2++)
#pragma unroll
      for (int ks = 0; ks < 2; ks++)
        b[n2][ks] = *(const short8*)(base + n2 * 2048 + (cbase ^ (ks << 6)));
  };
  auto MM = [&](int mq, short8 (&b)[2][2], int nq) {
    __builtin_amdgcn_s_setprio(1);
#pragma unroll
    for (int m2 = 0; m2 < 4; m2++)
#pragma unroll
      for (int n2 = 0; n2 < 2; n2++)
#pragma unroll
        for (int ks = 0; ks < 2; ks++)
          acc[mq * 4 + m2][nq * 2 + n2] = __builtin_amdgcn_mfma_f32_16x16x32_bf16(
              a[m2][ks], b[n2][ks], acc[mq * 4 + m2][nq * 2 + n2], 0, 0, 0);
    __builtin_amdgcn_s_setprio(0);
  };

  STG_A(0, 0, 0); STG_A(0, 1, 0); STG_B(0, 0, 0); STG_B(0, 1, 0);
  STG_B(1, 0, 1); STG_A(1, 0, 1);
  asm volatile("s_waitcnt vmcnt(4)" ::: "memory");
  __builtin_amdgcn_s_barrier();
  asm volatile("" ::: "memory");

  const int NT = 16;
#pragma unroll 1
  for (int kt = 0; kt < NT; kt++) {
    int buf = kt & 1;
    RD_A(0, buf); RD_B(blo, 0, buf);
    if (kt + 1 < NT) STG_A(kt + 1, 1, buf ^ 1);
    __builtin_amdgcn_s_barrier();
    asm volatile("" ::: "memory");
    MM(0, blo, 0);
    __builtin_amdgcn_s_barrier();
    asm volatile("" ::: "memory");
    RD_B(bhi, 1, buf);
    if (kt + 1 < NT) STG_B(kt + 1, 1, buf ^ 1);
    __builtin_amdgcn_s_barrier();
    asm volatile("" ::: "memory");
    MM(0, bhi, 1);
    __builtin_amdgcn_s_barrier();
    asm volatile("" ::: "memory");
    RD_A(1, buf);
    if (kt + 2 < NT) STG_B(kt + 2, 0, buf);
    __builtin_amdgcn_s_barrier();
    asm volatile("" ::: "memory");
    MM(1, bhi, 1);
    __builtin_amdgcn_s_barrier();
    asm volatile("" ::: "memory");
    if (kt + 2 < NT) STG_A(kt + 2, 0, buf);
    if (kt < NT - 2) {
      asm volatile("s_waitcnt vmcnt(4)" ::: "memory");
    } else if (kt == NT - 2) {
      asm volatile("s_waitcnt vmcnt(0)" ::: "memory");
    }
    __builtin_amdgcn_s_barrier();
    asm volatile("" ::: "memory");
    MM(1, blo, 0);
    __builtin_amdgcn_s_barrier();
    asm volatile("" ::: "memory");
  }

  unsigned short* yseg = y_buf + (size_t)kseg * MAXP * 1024;
#pragma unroll
  for (int mf = 0; mf < 8; mf++) {
#pragma unroll
    for (int nf = 0; nf < 4; nf++) {
      int col = nt * 256 + wn * 64 + nf * 16 + l15;
#pragma unroll
      for (int rr = 0; rr < 4; rr++) {
        int pos = row0 + wr * 128 + mf * 16 + g4 * 4 + rr;
        yseg[(size_t)pos * D_DIM + col] = f2bf(acc[mf][nf][rr]);
      }
    }
  }
}

// ---------------- combine: out[t] = w0*(y0[p0]+y1[p0]) + w1*(y0[p1]+y1[p1]) ----------------
__global__ void combine_kernel(const unsigned short* __restrict__ y_buf,
                               const int2* __restrict__ tok_pos, const float* __restrict__ tok_w,
                               float* __restrict__ out) {
  int t = blockIdx.x * 2 + (threadIdx.x >> 7);
  int c = (threadIdx.x & 127) * 8;
  int2 p = tok_pos[t];
  float w0 = tok_w[2 * t], w1 = tok_w[2 * t + 1];
  const unsigned short* y1 = y_buf + (size_t)MAXP * 1024;
  u16x8 a0 = *(const u16x8*)(y_buf + (size_t)p.x * D_DIM + c);
  u16x8 a1 = *(const u16x8*)(y1 + (size_t)p.x * D_DIM + c);
  u16x8 b0 = *(const u16x8*)(y_buf + (size_t)p.y * D_DIM + c);
  u16x8 b1 = *(const u16x8*)(y1 + (size_t)p.y * D_DIM + c);
  float o[8];
#pragma unroll
  for (int k = 0; k < 8; k++)
    o[k] = w0 * (bf2f(a0[k]) + bf2f(a1[k])) + w1 * (bf2f(b0[k]) + bf2f(b1[k]));
  float4* op = (float4*)(out + (size_t)t * D_DIM + c);
  op[0] = make_float4(o[0], o[1], o[2], o[3]);
  op[1] = make_float4(o[4], o[5], o[6], o[7]);
}

// ---------------- launch ----------------
extern "C" void kernel_launch(void* const* d_in, const int* in_sizes, int n_in,
                              void* d_out, int out_size, void* d_ws, size_t ws_size,
                              hipStream_t stream) {
  const float* x  = (const float*)d_in[0];
  const float* Wg = (const float*)d_in[1];
  const float* W1 = (const float*)d_in[2];
  const float* W2 = (const float*)d_in[3];
  const float* W3 = (const float*)d_in[4];
  float* out = (float*)d_out;

  char* ws = (char*)d_ws;
  size_t off = 0;
  auto alloc = [&](size_t bytes) -> char* {
    char* p = ws + off; off += (bytes + 255) & ~(size_t)255; return p;
  };

  int*            poffs      = (int*)alloc(16 * 4);
  int*            tile2e     = (int*)alloc(80 * 4);
  int*            tile_row0  = (int*)alloc(80 * 4);
  int*            chunk_base = (int*)alloc(NCHUNK * E_NUM * 4);
  int*            tok_e01    = (int*)alloc(T_TOKENS * 4);
  float*          tok_w      = (float*)alloc(T_TOKENS * 8);
  int2*           tok_pos    = (int2*)alloc(T_TOKENS * 8);
  int*            pair_tok   = (int*)alloc(MAXP * 4);
  unsigned short* xb         = (unsigned short*)alloc((size_t)T_TOKENS * D_DIM * 2);   // 16 MB
  unsigned short* Bcat       = (unsigned short*)alloc((size_t)E_NUM * 4096 * 1024 * 2); // 64 MB, directly after xb
  unsigned short* W3t        = (unsigned short*)alloc((size_t)E_NUM * D_DIM * H_DIM * 2);
  unsigned short* h_buf      = (unsigned short*)alloc((size_t)MAXP * H_DIM * 2);
  // y_buf needs 2 * MAXP * 1024 * 2B = 75.5 MB. Bcat alone is 64 MB (round-9/10 BUG:
  // overran into W3t). xb (16 MB) + Bcat (64 MB) are contiguous and both dead after
  // ffn1 -> 80 MB region starting at xb. W3t untouched.
  unsigned short* y_buf      = xb;

  hipFuncSetAttribute((const void*)ffn1_kernel, hipFuncAttributeMaxDynamicSharedMemorySize, 131072);
  hipFuncSetAttribute((const void*)ffn2_kernel, hipFuncAttributeMaxDynamicSharedMemorySize, 131072);

  hipMemsetAsync(pair_tok, 0, MAXP * 4, stream);

  router_kernel<<<T_TOKENS / 4, 256, 0, stream>>>(x, Wg, tok_e01, tok_w);
  hist_kernel<<<1, 1024, 0, stream>>>(tok_e01, poffs, tile2e, tile_row0, chunk_base);
  assign_kernel<<<NCHUNK, 256, 0, stream>>>(tok_e01, chunk_base, pair_tok, tok_pos);
  cast_x_kernel<<<(T_TOKENS * D_DIM / 8) / 256, 256, 0, stream>>>(x, xb);
  cast_transpose64_kernel<<<dim3(H_DIM / 64, D_DIM / 64, E_NUM), 256, 0, stream>>>(
      W1, Bcat, D_DIM, H_DIM, (size_t)4096 * 1024, 1, 0);
  cast_transpose64_kernel<<<dim3(H_DIM / 64, D_DIM / 64, E_NUM), 256, 0, stream>>>(
      W2, Bcat, D_DIM, H_DIM, (size_t)4096 * 1024, 1, 1);
  cast_transpose64_kernel<<<dim3(D_DIM / 64, H_DIM / 64, E_NUM), 256, 0, stream>>>(
      W3, W3t, H_DIM, D_DIM, (size_t)2048 * 1024, 0, 0);

  ffn1_kernel<<<dim3(MAXT * 16), 512, 131072, stream>>>(xb, Bcat, h_buf, pair_tok, tile2e, tile_row0);
  ffn2_kernel<<<dim3(MAXT * 8), 512, 131072, stream>>>(h_buf, W3t, y_buf, tile2e, tile_row0);
  combine_kernel<<<T_TOKENS / 2, 256, 0, stream>>>(y_buf, tok_pos, tok_w, out);
}